// Round 25
// baseline (545.894 us; speedup 1.0000x reference)
//
#include <hip/hip_runtime.h>
#include <math.h>

#define NA 8000
#define NV 4000
#define NN 12000
#define NA_PAD 8192
#define NV_PAD 4096
#define FEAT 32
#define HD 64
#define NLAYER 12
#define E_AA 80000
#define E_AV 120000
#define E_VV 60000
#define E_TOT 260000
#define ENC_SIZE (NV * HD)
#define EPS 1e-5f
#define NGRP (NN/4)

#define GDIM 8
#define NCELL 512
#define NGA (NA_PAD/64)   // 128 atom groups
#define NGV (NV_PAD/64)   // 64 vox groups
#define PADPOS 1e30f
#define KNN_LDS (2048*16 + 2048*4 + 16*4)

__device__ __forceinline__ float wave_sum64(float v) {
#pragma unroll
  for (int off = 1; off < 64; off <<= 1) v += __shfl_xor(v, off);
  return v;
}

// DPP butterfly helpers: pure VALU (v_add_f32_dpp), no DS pipe.
__device__ __forceinline__ float dpp_step(float v, const int ctrl) {
  int p;
  switch (ctrl) {
    case 0xB1:  p = __builtin_amdgcn_update_dpp(0, __float_as_int(v), 0xB1,  0xF, 0xF, true); break;
    case 0x4E:  p = __builtin_amdgcn_update_dpp(0, __float_as_int(v), 0x4E,  0xF, 0xF, true); break;
    case 0x141: p = __builtin_amdgcn_update_dpp(0, __float_as_int(v), 0x141, 0xF, 0xF, true); break;
    default:    p = __builtin_amdgcn_update_dpp(0, __float_as_int(v), 0x140, 0xF, 0xF, true); break;
  }
  return v + __int_as_float(p);
}

__device__ __forceinline__ float head_sum16_dpp(float v) {
  v = dpp_step(v, 0xB1);
  v = dpp_step(v, 0x4E);
  v = dpp_step(v, 0x141);
  v = dpp_step(v, 0x140);
  return v;
}

__device__ __forceinline__ float wave_sum64_dpp(float v) {
  v = head_sum16_dpp(v);
  v += __shfl_xor(v, 16);
  v += __shfl_xor(v, 32);
  return v;
}

__device__ __forceinline__ int cell_of(float x, float y, float z) {
  int ix = (int)((x + 6.0f) * (GDIM / 12.0f));
  int iy = (int)((y + 6.0f) * (GDIM / 12.0f));
  int iz = (int)((z + 6.0f) * (GDIM / 12.0f));
  ix = min(max(ix, 0), GDIM-1); iy = min(max(iy, 0), GDIM-1);
  iz = min(max(iz, 0), GDIM-1);
  int m = 0;
#pragma unroll
  for (int b = 0; b < 3; ++b) {
    m |= ((ix>>b)&1) << (3*b);
    m |= ((iy>>b)&1) << (3*b+1);
    m |= ((iz>>b)&1) << (3*b+2);
  }
  return m;
}

// ---------------------------------------------------------------------------
// Pack candidates as [x,y,z,|c|^2] (FROZEN expression — sole producer of
// packed bits; scatter copies these verbatim).
// ---------------------------------------------------------------------------
__global__ __launch_bounds__(256) void pack_kernel(
    const float* __restrict__ apos, const float* __restrict__ vpos,
    float4* __restrict__ apk, float4* __restrict__ vpk)
{
  const int i = blockIdx.x * 256 + threadIdx.x;
  if (i < NA_PAD) {
    float4 r;
    if (i < NA) {
      const float cx = apos[i*3+0], cy = apos[i*3+1], cz = apos[i*3+2];
      r = make_float4(cx, cy, cz, (cx*cx + cy*cy) + cz*cz);
    } else r = make_float4(0.f, 0.f, 0.f, INFINITY);
    apk[i] = r;
  } else {
    const int j = i - NA_PAD;
    if (j < NV_PAD) {
      float4 r;
      if (j < NV) {
        const float cx = vpos[j*3+0], cy = vpos[j*3+1], cz = vpos[j*3+2];
        r = make_float4(cx, cy, cz, (cx*cx + cy*cy) + cz*cz);
      } else r = make_float4(0.f, 0.f, 0.f, INFINITY);
      vpk[j] = r;
    }
  }
}

// ---------------------------------------------------------------------------
// Grid prep: counting-sort by Morton cell (scatter COPIES packed float4 so
// candidate bits are identical by construction) + pad-aware group AABBs.
// ---------------------------------------------------------------------------
__global__ __launch_bounds__(256) void prep_zero_kernel(
    int* __restrict__ aHist, int* __restrict__ vHist,
    float4* __restrict__ aS, int* __restrict__ aO,
    float4* __restrict__ vS, int* __restrict__ vO)
{
  const int i = blockIdx.x * 256 + threadIdx.x;
  if (i < NCELL) aHist[i] = 0;
  else if (i < 2*NCELL) vHist[i - NCELL] = 0;
  if (i >= NA && i < NA_PAD) {
    aS[i] = make_float4(PADPOS, PADPOS, PADPOS, INFINITY); aO[i] = 0x7fffffff;
  }
  if (i >= NV && i < NV_PAD) {
    vS[i] = make_float4(PADPOS, PADPOS, PADPOS, INFINITY); vO[i] = 0x7fffffff;
  }
}

__global__ __launch_bounds__(256) void cell_count_kernel(
    const float* __restrict__ apos, const float* __restrict__ vpos,
    int* __restrict__ aHist, int* __restrict__ vHist)
{
  const int i = blockIdx.x * 256 + threadIdx.x;
  if (i < NA) {
    atomicAdd(aHist + cell_of(apos[i*3], apos[i*3+1], apos[i*3+2]), 1);
  } else if (i < NA + NV) {
    const int j = i - NA;
    atomicAdd(vHist + cell_of(vpos[j*3], vpos[j*3+1], vpos[j*3+2]), 1);
  }
}

__global__ __launch_bounds__(512) void cell_scan_kernel(
    const int* __restrict__ aHist, int* __restrict__ aStart, int* __restrict__ aCur,
    const int* __restrict__ vHist, int* __restrict__ vStart, int* __restrict__ vCur)
{
  __shared__ int tmp[NCELL];
  const int* hist; int* start; int* cur;
  if (blockIdx.x == 0) { hist = aHist; start = aStart; cur = aCur; }
  else                 { hist = vHist; start = vStart; cur = vCur; }
  const int t = threadIdx.x;
  const int v = hist[t];
  tmp[t] = v;
  __syncthreads();
  for (int off = 1; off < NCELL; off <<= 1) {
    const int u = (t >= off) ? tmp[t - off] : 0;
    __syncthreads();
    tmp[t] += u;
    __syncthreads();
  }
  const int excl = tmp[t] - v;
  start[t] = excl; cur[t] = excl;
}

__global__ __launch_bounds__(256) void cell_scatter_kernel(
    const float4* __restrict__ apk, const float4* __restrict__ vpk,
    int* __restrict__ aCur, int* __restrict__ vCur,
    float4* __restrict__ aS, int* __restrict__ aO,
    float4* __restrict__ vS, int* __restrict__ vO)
{
  const int i = blockIdx.x * 256 + threadIdx.x;
  if (i < NA) {
    const float4 c = apk[i];                   // copy packed bits verbatim
    const int cell = cell_of(c.x, c.y, c.z);
    const int s = atomicAdd(aCur + cell, 1);
    aS[s] = c; aO[s] = i;
  } else if (i < NA + NV) {
    const int j = i - NA;
    const float4 c = vpk[j];
    const int cell = cell_of(c.x, c.y, c.z);
    const int s = atomicAdd(vCur + cell, 1);
    vS[s] = c; vO[s] = j;
  }
}

// Pad-aware group AABBs: pad lanes contribute +INF to min, -INF to max, so
// all-pad groups get inverted boxes (gd2=inf -> always pruned) and mixed
// groups get boxes over real members only.
__global__ __launch_bounds__(64) void group_bb_kernel(
    const float4* __restrict__ aS, const int* __restrict__ aO, float4* __restrict__ agbb,
    const float4* __restrict__ vS, const int* __restrict__ vO, float4* __restrict__ vgbb)
{
  const int g = blockIdx.x;
  const float4* S; const int* O; float4* B; int gg;
  if (g < NGA) { S = aS; O = aO; B = agbb; gg = g; }
  else         { S = vS; O = vO; B = vgbb; gg = g - NGA; }
  const float4 c = S[gg*64 + threadIdx.x];
  const bool pad = (O[gg*64 + threadIdx.x] == 0x7fffffff);
  float mnx = pad ?  1e30f : c.x, mxx = pad ? -1e30f : c.x;
  float mny = pad ?  1e30f : c.y, mxy = pad ? -1e30f : c.y;
  float mnz = pad ?  1e30f : c.z, mxz = pad ? -1e30f : c.z;
#pragma unroll
  for (int off = 1; off < 64; off <<= 1) {
    mnx = fminf(mnx, __shfl_xor(mnx, off)); mxx = fmaxf(mxx, __shfl_xor(mxx, off));
    mny = fminf(mny, __shfl_xor(mny, off)); mxy = fmaxf(mxy, __shfl_xor(mxy, off));
    mnz = fminf(mnz, __shfl_xor(mnz, off)); mxz = fmaxf(mxz, __shfl_xor(mxz, off));
  }
  if (threadIdx.x == 0) {
    B[2*gg]   = make_float4(mnx, mny, mnz, 0.f);
    B[2*gg+1] = make_float4(mxx, mxy, mxz, 0.f);
  }
}

// ---------------------------------------------------------------------------
// SORTED-SCAN kNN: frozen tile structure (LDS-staged 2048-candidate tiles,
// pipelined examines) over the Morton-sorted array, with conservative
// pruning: block-uniform staging skip + per-64-chunk skip, both via group
// AABB distance > thrD + slack (r23/r24-verified slack). Queries processed
// in SORTED order (block = 8 coherent queries) with tile order rotated to
// the query region so thrD collapses in the first tile. Examine body is
// the r23 probe-verified forced-intrinsic d2 + <= ballot + (d2,idx) insert;
// groups disjoint -> no duplicate inserts; selection order-independent.
// ---------------------------------------------------------------------------
template<int K, int NC_PAD, int SLOTS, bool ROTCELL>
__device__ __attribute__((noinline)) void knn_sorted_body(
    const float* __restrict__ qpos, const int* __restrict__ qO,
    const float4* __restrict__ cS, const int* __restrict__ cO,
    const float4* __restrict__ gbb, const int* __restrict__ cstart,
    int c_off, int* __restrict__ out_src, int qblock)
{
  extern __shared__ char ldsraw[];
  float4* tile = (float4*)ldsraw;           // [2048]
  int*    tidx = (int*)(tile + 2048);       // [2048]
  int*    comm = tidx + 2048;               // [16]

  const int tid = threadIdx.x, wid = tid >> 6, lane = tid & 63;
  const int sq = qblock*8 + wid;            // sorted query index
  const int oq = qO[sq];                    // original query id
  const float qx = qpos[oq*3+0], qy = qpos[oq*3+1], qz = qpos[oq*3+2];
  float qt = __fmul_rn(qx, qx);
  qt = __fmaf_rn(qy, qy, qt);
  const float qq = __fmaf_rn(qz, qz, qt);

  float eD = INFINITY; int eI = 0x7fffffff;
  float thrD = INFINITY;

  // lane-parallel group AABB distances (group id = slot*64 + lane)
  float gd0, gd1 = INFINITY;
  {
    const float4 mn = gbb[2*lane], mx = gbb[2*lane+1];
    const float ex = fmaxf(fmaxf(mn.x - qx, qx - mx.x), 0.f);
    const float ey = fmaxf(fmaxf(mn.y - qy, qy - mx.y), 0.f);
    const float ez = fmaxf(fmaxf(mn.z - qz, qz - mx.z), 0.f);
    gd0 = (ex*ex + ey*ey) + ez*ez;
  }
  if (SLOTS == 2) {
    const float4 mn = gbb[2*(64+lane)], mx = gbb[2*(64+lane)+1];
    const float ex = fmaxf(fmaxf(mn.x - qx, qx - mx.x), 0.f);
    const float ey = fmaxf(fmaxf(mn.y - qy, qy - mx.y), 0.f);
    const float ez = fmaxf(fmaxf(mn.z - qz, qz - mx.z), 0.f);
    gd1 = (ex*ex + ey*ey) + ez*ez;
  }

  const int NTILES = NC_PAD / 2048;
  if (tid == 0) {
    int ts;
    if (ROTCELL) ts = cstart[cell_of(qx, qy, qz)] >> 11;
    else         ts = (qblock*8) >> 11;
    if (ts >= NTILES) ts = NTILES - 1;
    comm[8] = ts;
  }
  __syncthreads();
  const int tstart = comm[8];

  for (int ti = 0; ti < NTILES; ++ti) {
    int t = tstart + ti; if (t >= NTILES) t -= NTILES;
    const int t0 = t * 2048;
    // wave need flag: any of this tile's 32 groups within thrD+slack
    const int slot = t >> 1;
    const int laneoff = (t & 1) * 32;
    const float myg = (slot == 0) ? gd0 : gd1;
    const bool ql = (lane >= laneoff) && (lane < laneoff + 32) &&
                    (myg <= thrD + (1e-4f + 1e-6f*thrD));
    const bool need = (__ballot(ql) != 0ULL);
    if (lane == 0) comm[wid] = need ? 1 : 0;
    __syncthreads();
    int bn = 0;
#pragma unroll
    for (int w = 0; w < 8; ++w) bn |= comm[w];
    if (bn) {
#pragma unroll
      for (int s = 0; s < 4; ++s) tile[s*512 + tid] = cS[t0 + s*512 + tid];
#pragma unroll
      for (int s = 0; s < 4; ++s) tidx[s*512 + tid] = cO[t0 + s*512 + tid];
    }
    __syncthreads();
    if (need) {
      for (int it = 0; it < 32; ++it) {
        const int g = t*32 + it;
        const float gsrc = ((g >> 6) == 0) ? gd0 : gd1;
        const float gg = __shfl(gsrc, g & 63);
        if (gg > thrD + (1e-4f + 1e-6f*thrD)) continue;   // conservative skip
        const float4 c = tile[it*64 + lane];
        const int oidx = tidx[it*64 + lane];
        float t1 = __fmul_rn(qx, c.x);
        t1 = __fmaf_rn(qy, c.y, t1);
        const float dot = __fmaf_rn(qz, c.z, t1);
        const float d2  = __fadd_rn(__fmaf_rn(-2.0f, dot, qq), c.w);
        unsigned long long m = __ballot(d2 <= thrD);
        if (m) {
          do {                                 // wave-uniform insert loop
            const int sl = __ffsll(m) - 1;
            m &= (m - 1ULL);
            const float v  = __shfl(d2, sl);
            const int   vi = __shfl(oidx, sl);
            const bool stay = (eD < v) || (eD == v && eI < vi);
            const float pD = __shfl_up(eD, 1);
            const int   pI = __shfl_up(eI, 1);
            int pS = __shfl_up(stay ? 1 : 0, 1);
            if (lane == 0) pS = 1;
            eD = stay ? eD : (pS ? v  : pD);
            eI = stay ? eI : (pS ? vi : pI);
          } while (m);
          thrD = __shfl(eD, K-1);
        }
      }
    }
    __syncthreads();                           // comm reuse next iteration
  }
  if (lane < K) out_src[oq*K + lane] = eI + c_off;
}

__global__ __launch_bounds__(512) void knn_sorted_all_kernel(
    const float* __restrict__ apos, const float* __restrict__ vpos,
    const float4* __restrict__ aS, const int* __restrict__ aO,
    const float4* __restrict__ vS, const int* __restrict__ vO,
    const float4* __restrict__ agbb, const float4* __restrict__ vgbb,
    const int* __restrict__ vStart,
    int* __restrict__ srcA, int* __restrict__ srcAV, int* __restrict__ srcVV)
{
  const int b = blockIdx.x;                   // block-uniform branch
  if (b < NA/8)
    knn_sorted_body<10, NA_PAD, 2, false>(apos, aO, aS, aO, agbb, nullptr,
                                          0, srcA, b);
  else if (b < 2*(NA/8))
    knn_sorted_body<15, NV_PAD, 1, true>(apos, aO, vS, vO, vgbb, vStart,
                                         NA, srcAV, b - NA/8);
  else
    knn_sorted_body<15, NV_PAD, 1, false>(vpos, vO, vS, vO, vgbb, nullptr,
                                          NA, srcVV, b - 2*(NA/8));
}

// ---------------------------------------------------------------------------
// LayerNorm + s/d projection, single-wave version (used by init only).
// ---------------------------------------------------------------------------
__device__ __forceinline__ void ln_sd(
    float v, int node, int lane, int l,
    const float* __restrict__ ln_g, const float* __restrict__ ln_b,
    const float* __restrict__ Ws, const float* __restrict__ Wd,
    float* __restrict__ sbuf, float* __restrict__ dbuf)
{
  const float m = wave_sum64_dpp(v) * (1.0f/64.0f);
  const float c = v - m;
  const float var = wave_sum64_dpp(c*c) * (1.0f/64.0f);
  const float hn = c * rsqrtf(var + EPS) * ln_g[l*HD + lane] + ln_b[l*HD + lane];
  const float* ws = Ws + (size_t)l*HD*HD;
  const float* wd = Wd + (size_t)l*HD*HD;
  float accs = 0.0f, accd = 0.0f;
#pragma unroll
  for (int j = 0; j < HD; ++j) {
    const float hj = __shfl(hn, j);
    accs += hj * ws[j*HD + lane];
    accd += hj * wd[j*HD + lane];
  }
  sbuf[node*HD + lane] = accs;
  dbuf[node*HD + lane] = accd;
}

// ---------------------------------------------------------------------------
// Fused first kernel: input projection + snapshot0 + LN(0) + s/d projection.
// ---------------------------------------------------------------------------
__global__ __launch_bounds__(64) void init_kernel(
    const float* __restrict__ atom_x, const float* __restrict__ vox_x,
    const float* __restrict__ Wa, const float* __restrict__ ba,
    const float* __restrict__ Wv, const float* __restrict__ bv,
    const float* __restrict__ ln_g, const float* __restrict__ ln_b,
    const float* __restrict__ Ws, const float* __restrict__ Wd,
    float* __restrict__ x, float* __restrict__ snap0,
    float* __restrict__ sbuf, float* __restrict__ dbuf)
{
  const int node = blockIdx.x;
  const int t    = threadIdx.x;
  const float* in; const float* W; const float* b;
  if (node < NA) { in = atom_x + node*FEAT;     W = Wa; b = ba; }
  else           { in = vox_x + (node-NA)*FEAT; W = Wv; b = bv; }
  float acc = b[t];
#pragma unroll
  for (int j = 0; j < FEAT; ++j) acc += in[j] * W[j*HD + t];
  x[node*HD + t] = acc;
  if (node >= NA) snap0[(node-NA)*HD + t] = acc;
  ln_sd(acc, node, t, 0, ln_g, ln_b, Ws, Wd, sbuf, dbuf);
}

// ---------------------------------------------------------------------------
// Edge attribute MLP.
// ---------------------------------------------------------------------------
__device__ __forceinline__ void load_pos(const float* ap, const float* vp,
                                         int i, float& px, float& py, float& pz)
{
  const float* p = (i < NA) ? (ap + i*3) : (vp + (i - NA)*3);
  px = p[0]; py = p[1]; pz = p[2];
}

__global__ __launch_bounds__(256) void edge_attr_kernel(
    const float* __restrict__ atom_pos, const float* __restrict__ vox_pos,
    const int* __restrict__ srcA, const int* __restrict__ srcAV,
    const int* __restrict__ srcVV,
    const float* __restrict__ w1, const float* __restrict__ b1,
    const float* __restrict__ w2, const float* __restrict__ b2,
    float* __restrict__ eattr)
{
  const int e = blockIdx.x * 256 + threadIdx.x;
  if (e >= E_TOT) return;
  int s, d, mi;
  if (e < E_AA)              { mi = 0; s = srcA[e];                 d = e / 10; }
  else if (e < E_AA + E_AV)  { mi = 1; const int t = e - E_AA;      s = srcAV[t]; d = t / 15; }
  else                       { mi = 2; const int t = e - E_AA - E_AV; s = srcVV[t]; d = NA + t / 15; }
  float sx, sy, sz, dx_, dy_, dz_;
  load_pos(atom_pos, vox_pos, s, sx, sy, sz);
  load_pos(atom_pos, vox_pos, d, dx_, dy_, dz_);
  const float ex = sx - dx_, ey = sy - dy_, ez = sz - dz_;
  const float dist = sqrtf(ex*ex + ey*ey + ez*ez);
  float acc = b2[mi];
#pragma unroll
  for (int j = 0; j < 8; ++j) {
    float h = dist * w1[mi*8 + j] + b1[mi*8 + j];
    h = (h > 0.0f) ? h : 0.0f;
    acc += h * w2[mi*8 + j];
  }
  eattr[e] = acc;
}

// ---------------------------------------------------------------------------
// Per-node attention aggregation (r16/17, passing).
// ---------------------------------------------------------------------------
template<int NE, bool IS_ATOM>
__device__ __forceinline__ float agg_node(
    int n, int lane,
    float* __restrict__ x,
    const float* __restrict__ sbuf, const float* __restrict__ dbuf,
    const float* __restrict__ eattr,
    const int* __restrict__ srcA, const int* __restrict__ srcAV,
    const int* __restrict__ srcVV,
    const float* __restrict__ We, const float* __restrict__ att, int l,
    float* __restrict__ snap)
{
  const float wet  = We[l*HD + lane];
  const float attv = att[l*HD + lane];
  const float dn   = dbuf[n*HD + lane];

  int esrc[NE]; float eat[NE];
#pragma unroll
  for (int e = 0; e < NE; ++e) {
    int src, eidx;
    if (IS_ATOM) {
      if (e < 10) { src = srcA[n*10 + e];       eidx = n*10 + e; }
      else        { src = srcAV[n*15 + (e-10)]; eidx = E_AA + n*15 + (e-10); }
    } else {
      const int nv = n - NA;
      src = srcVV[nv*15 + e]; eidx = E_AA + E_AV + nv*15 + e;
    }
    esrc[e] = src;
    eat[e]  = eattr[eidx];
  }

  float srow[NE];
#pragma unroll
  for (int e = 0; e < NE; ++e) srow[e] = sbuf[esrc[e]*HD + lane];

  float escore[NE];
#pragma unroll
  for (int e = 0; e < NE; ++e) {
    float mm = srow[e] + dn + eat[e] * wet;
    mm = (mm >= 0.0f) ? mm : 0.2f * mm;        // leaky_relu(0.2)
    escore[e] = head_sum16_dpp(mm * attv);
  }
  float mx = -INFINITY;
#pragma unroll
  for (int e = 0; e < NE; ++e) mx = fmaxf(mx, escore[e]);
  float den = 0.0f;
#pragma unroll
  for (int e = 0; e < NE; ++e) {
    const float a = __expf(escore[e] - mx);
    escore[e] = a; den += a;
  }
  const float inv = 1.0f / den;
  float msg = 0.0f;
#pragma unroll
  for (int e = 0; e < NE; ++e) msg += (escore[e] * inv) * srow[e];
  float xv = x[n*HD + lane] + msg;
  xv = (xv > 0.0f) ? xv : 0.0f;
  x[n*HD + lane] = xv;
  if (!IS_ATOM && snap != nullptr) snap[(n - NA)*HD + lane] = xv;
  return xv;
}

// ---------------------------------------------------------------------------
// Fused layer (r17/18/21 verbatim).
// ---------------------------------------------------------------------------
__global__ __launch_bounds__(256, 4) void layer_kernel(
    float* __restrict__ x,
    const float* __restrict__ sbuf_in, float* __restrict__ dbuf,
    float* __restrict__ sbuf_out,
    const float* __restrict__ eattr,
    const int* __restrict__ srcA, const int* __restrict__ srcAV,
    const int* __restrict__ srcVV,
    const float* __restrict__ We, const float* __restrict__ att,
    const float* __restrict__ ln_g, const float* __restrict__ ln_b,
    const float* __restrict__ Ws, const float* __restrict__ Wd,
    int l, float* __restrict__ snap, int do_next)
{
  const int wid = threadIdx.x >> 6, lane = threadIdx.x & 63;
  const int n = blockIdx.x * 4 + wid;
  __shared__ float hn_sh[HD][4];
  __shared__ float part[4][4][2][HD];

  float xv;
  if (n < NA) {
    if (!do_next) return;
    xv = agg_node<25,true>(n, lane, x, sbuf_in, dbuf, eattr,
                           srcA, srcAV, srcVV, We, att, l, nullptr);
  } else {
    xv = agg_node<15,false>(n, lane, x, sbuf_in, dbuf, eattr,
                            srcA, srcAV, srcVV, We, att, l, snap);
  }
  if (!do_next) return;

  const int ln = l + 1;
  const float mean = wave_sum64_dpp(xv) * (1.0f/64.0f);
  const float cc   = xv - mean;
  const float var  = wave_sum64_dpp(cc*cc) * (1.0f/64.0f);
  const float hn   = cc * rsqrtf(var + EPS) * ln_g[ln*HD + lane] + ln_b[ln*HD + lane];
  hn_sh[lane][wid] = hn;
  __syncthreads();

  const float* wsp = Ws + (size_t)ln*HD*HD;
  const float* wdp = Wd + (size_t)ln*HD*HD;
  float as0=0.f, as1=0.f, as2=0.f, as3=0.f;
  float ad0=0.f, ad1=0.f, ad2=0.f, ad3=0.f;
#pragma unroll
  for (int jj = 0; jj < 16; ++jj) {
    const int j = wid*16 + jj;
    const float wvs = wsp[j*HD + lane];
    const float wvd = wdp[j*HD + lane];
    const float4 h = *(const float4*)&hn_sh[j][0];
    as0 += h.x*wvs; ad0 += h.x*wvd;
    as1 += h.y*wvs; ad1 += h.y*wvd;
    as2 += h.z*wvs; ad2 += h.z*wvd;
    as3 += h.w*wvs; ad3 += h.w*wvd;
  }
  part[wid][0][0][lane] = as0; part[wid][0][1][lane] = ad0;
  part[wid][1][0][lane] = as1; part[wid][1][1][lane] = ad1;
  part[wid][2][0][lane] = as2; part[wid][2][1][lane] = ad2;
  part[wid][3][0][lane] = as3; part[wid][3][1][lane] = ad3;
  __syncthreads();

  const float accs = ((part[0][wid][0][lane] + part[1][wid][0][lane])
                    + (part[2][wid][0][lane] + part[3][wid][0][lane]));
  const float accd = ((part[0][wid][1][lane] + part[1][wid][1][lane])
                    + (part[2][wid][1][lane] + part[3][wid][1][lane]));
  sbuf_out[n*HD + lane] = accs;
  dbuf[n*HD + lane]     = accd;
}

// ---------------------------------------------------------------------------
// Output head.
// ---------------------------------------------------------------------------
__global__ __launch_bounds__(256) void head_kernel(
    const float* __restrict__ snaps,
    const float* __restrict__ Wo1, const float* __restrict__ bo1,
    const float* __restrict__ Wo2, const float* __restrict__ bo2,
    float* __restrict__ out)
{
  const int wid = threadIdx.x >> 6, lane = threadIdx.x & 63;
  const int n = blockIdx.x * 4 + wid;
  __shared__ float cat[4][7*HD];
  __shared__ float part[4][4][HD];
  __shared__ float o1[4][HD];

#pragma unroll
  for (int c = 0; c < 7; ++c)
    cat[wid][c*HD + lane] = snaps[(size_t)c*NV*HD + n*HD + lane];
  __syncthreads();

  float a0=0.f, a1=0.f, a2=0.f, a3=0.f;
  for (int jj = 0; jj < 112; ++jj) {
    const int j = wid*112 + jj;
    const float w = Wo1[j*HD + lane];
    a0 += cat[0][j]*w; a1 += cat[1][j]*w;
    a2 += cat[2][j]*w; a3 += cat[3][j]*w;
  }
  part[wid][0][lane] = a0; part[wid][1][lane] = a1;
  part[wid][2][lane] = a2; part[wid][3][lane] = a3;
  __syncthreads();

  float acc = bo1[lane] + ((part[0][wid][lane] + part[1][wid][lane])
                         + (part[2][wid][lane] + part[3][wid][lane]));
  acc = fmaxf(acc, 0.0f);
  o1[wid][lane] = acc;
  __syncthreads();

  float b0=0.f, b1=0.f, b2=0.f, b3=0.f;
#pragma unroll
  for (int jj = 0; jj < 16; ++jj) {
    const int j = wid*16 + jj;
    const float w = Wo2[j*HD + lane];
    b0 += o1[0][j]*w; b1 += o1[1][j]*w;
    b2 += o1[2][j]*w; b3 += o1[3][j]*w;
  }
  __syncthreads();
  part[wid][0][lane] = b0; part[wid][1][lane] = b1;
  part[wid][2][lane] = b2; part[wid][3][lane] = b3;
  __syncthreads();

  const float acc2 = bo2[lane] + ((part[0][wid][lane] + part[1][wid][lane])
                                + (part[2][wid][lane] + part[3][wid][lane]));
  out[n*HD + lane] = acc2;
}

__global__ __launch_bounds__(256) void copy_pos_kernel(
    const float* __restrict__ vp, float* __restrict__ out)
{
  const int i = blockIdx.x * 256 + threadIdx.x;
  if (i < NV*3) out[ENC_SIZE + i] = vp[i];
}

// ---------------------------------------------------------------------------
extern "C" void kernel_launch(void* const* d_in, const int* in_sizes, int n_in,
                              void* d_out, int out_size, void* d_ws, size_t ws_size,
                              hipStream_t stream)
{
  const float* atom_x    = (const float*)d_in[0];
  const float* atom_pos  = (const float*)d_in[1];
  const float* vox_x     = (const float*)d_in[2];
  const float* vox_pos   = (const float*)d_in[3];
  const float* W_atom_in = (const float*)d_in[4];
  const float* b_atom_in = (const float*)d_in[5];
  const float* W_vox_in  = (const float*)d_in[6];
  const float* b_vox_in  = (const float*)d_in[7];
  const float* emlp_w1   = (const float*)d_in[8];
  const float* emlp_b1   = (const float*)d_in[9];
  const float* emlp_w2   = (const float*)d_in[10];
  const float* emlp_b2   = (const float*)d_in[11];
  const float* ln_g      = (const float*)d_in[12];
  const float* ln_b      = (const float*)d_in[13];
  const float* Ws        = (const float*)d_in[14];
  const float* Wd        = (const float*)d_in[15];
  const float* We        = (const float*)d_in[16];
  const float* att       = (const float*)d_in[17];
  const float* Wo1       = (const float*)d_in[18];
  const float* bo1       = (const float*)d_in[19];
  const float* Wo2       = (const float*)d_in[20];
  const float* bo2       = (const float*)d_in[21];
  float* out = (float*)d_out;

  // workspace layout (floats), ~22 MB
  float* ws    = (float*)d_ws;
  float* x     = ws;                          // [NN][HD]
  float* sA    = x  + (size_t)NN*HD;
  float* sB    = sA + (size_t)NN*HD;
  float* dbuf  = sB + (size_t)NN*HD;
  float* eattr = dbuf + (size_t)NN*HD;        // [E_TOT]
  float* snaps = eattr + E_TOT;               // [7][NV][HD]
  int*   srcA  = (int*)(snaps + (size_t)7*NV*HD);
  int*   srcAV = srcA  + E_AA;
  int*   srcVV = srcAV + E_AV;
  int*   aHist = srcVV + E_VV;                // [512] x6
  int*   vHist = aHist + NCELL;
  int*   aStart= vHist + NCELL;
  int*   vStart= aStart + NCELL;
  int*   aCur  = vStart + NCELL;
  int*   vCur  = aCur + NCELL;
  int*   aOrig = vCur + NCELL;                // [NA_PAD]
  int*   vOrig = aOrig + NA_PAD;              // [NV_PAD]
  float4* apk  = (float4*)(vOrig + NV_PAD);   // [NA_PAD]
  float4* vpk  = apk + NA_PAD;                // [NV_PAD]
  float4* aS   = vpk + NV_PAD;                // [NA_PAD]
  float4* vS   = aS + NA_PAD;                 // [NV_PAD]
  float4* agbb = vS + NV_PAD;                 // [2*NGA]
  float4* vgbb = agbb + 2*NGA;                // [2*NGV]

  // 1. pack + Morton counting-sort + pad-aware group AABBs + sorted-scan kNN
  pack_kernel<<<(NA_PAD + NV_PAD + 255)/256, 256, 0, stream>>>(
      atom_pos, vox_pos, apk, vpk);
  prep_zero_kernel<<<NA_PAD/256, 256, 0, stream>>>(aHist, vHist, aS, aOrig, vS, vOrig);
  cell_count_kernel<<<(NA+NV+255)/256, 256, 0, stream>>>(atom_pos, vox_pos, aHist, vHist);
  cell_scan_kernel<<<2, NCELL, 0, stream>>>(aHist, aStart, aCur, vHist, vStart, vCur);
  cell_scatter_kernel<<<(NA+NV+255)/256, 256, 0, stream>>>(
      apk, vpk, aCur, vCur, aS, aOrig, vS, vOrig);
  group_bb_kernel<<<NGA+NGV, 64, 0, stream>>>(aS, aOrig, agbb, vS, vOrig, vgbb);
  knn_sorted_all_kernel<<<NA/8 + NA/8 + NV/8, 512, KNN_LDS, stream>>>(
      atom_pos, vox_pos, aS, aOrig, vS, vOrig, agbb, vgbb, vStart,
      srcA, srcAV, srcVV);
  // 2. edge attributes
  edge_attr_kernel<<<(E_TOT + 255)/256, 256, 0, stream>>>(
      atom_pos, vox_pos, srcA, srcAV, srcVV,
      emlp_w1, emlp_b1, emlp_w2, emlp_b2, eattr);
  // 3. fused input proj + LN0 + s/d proj
  init_kernel<<<NN, 64, 0, stream>>>(atom_x, vox_x, W_atom_in, b_atom_in,
                                     W_vox_in, b_vox_in, ln_g, ln_b, Ws, Wd,
                                     x, snaps, sA, dbuf);
  // 4. 12 fused GAT layers (per-layer dispatch keeps L2 warm)
  for (int l = 0; l < NLAYER; ++l) {
    float* s_in  = (l & 1) ? sB : sA;
    float* s_out = (l & 1) ? sA : sB;
    float* snap  = (l & 1) ? (snaps + (size_t)(l/2 + 1)*NV*HD) : nullptr;
    layer_kernel<<<NGRP, 256, 0, stream>>>(x, s_in, dbuf, s_out, eattr,
                                           srcA, srcAV, srcVV, We, att,
                                           ln_g, ln_b, Ws, Wd, l, snap,
                                           (l < NLAYER-1) ? 1 : 0);
  }
  // 5. output head + vox_pos passthrough
  head_kernel<<<NV/4, 256, 0, stream>>>(snaps, Wo1, bo1, Wo2, bo2, out);
  copy_pos_kernel<<<(NV*3 + 255)/256, 256, 0, stream>>>(vox_pos, out);
}

// Round 26
// 392.195 us; speedup vs baseline: 1.3919x; 1.3919x over previous
//
#include <hip/hip_runtime.h>
#include <math.h>

#define NA 8000
#define NV 4000
#define NN 12000
#define NA_PAD 8192
#define NV_PAD 4096
#define KNN_TILE 2048
#define FEAT 32
#define HD 64
#define NLAYER 12
#define E_AA 80000
#define E_AV 120000
#define E_VV 60000
#define E_TOT 260000
#define ENC_SIZE (NV * HD)
#define EPS 1e-5f
#define NGRP (NN/4)

__device__ __forceinline__ float wave_sum64(float v) {
#pragma unroll
  for (int off = 1; off < 64; off <<= 1) v += __shfl_xor(v, off);
  return v;
}

// DPP butterfly helpers: pure VALU (v_add_f32_dpp), no DS pipe.
__device__ __forceinline__ float dpp_step(float v, const int ctrl) {
  int p;
  switch (ctrl) {
    case 0xB1:  p = __builtin_amdgcn_update_dpp(0, __float_as_int(v), 0xB1,  0xF, 0xF, true); break;
    case 0x4E:  p = __builtin_amdgcn_update_dpp(0, __float_as_int(v), 0x4E,  0xF, 0xF, true); break;
    case 0x141: p = __builtin_amdgcn_update_dpp(0, __float_as_int(v), 0x141, 0xF, 0xF, true); break;
    default:    p = __builtin_amdgcn_update_dpp(0, __float_as_int(v), 0x140, 0xF, 0xF, true); break;
  }
  return v + __int_as_float(p);
}

__device__ __forceinline__ float head_sum16_dpp(float v) {
  v = dpp_step(v, 0xB1);
  v = dpp_step(v, 0x4E);
  v = dpp_step(v, 0x141);
  v = dpp_step(v, 0x140);
  return v;
}

__device__ __forceinline__ float wave_sum64_dpp(float v) {
  v = head_sum16_dpp(v);
  v += __shfl_xor(v, 16);
  v += __shfl_xor(v, 32);
  return v;
}

// ---------------------------------------------------------------------------
// Pack candidate positions as [x, y, z, |c|^2] float4, padded with cc=+INF.
// (FROZEN)
// ---------------------------------------------------------------------------
__global__ __launch_bounds__(256) void pack_kernel(
    const float* __restrict__ apos, const float* __restrict__ vpos,
    float4* __restrict__ apk, float4* __restrict__ vpk)
{
  const int i = blockIdx.x * 256 + threadIdx.x;
  if (i < NA_PAD) {
    float4 r;
    if (i < NA) {
      const float cx = apos[i*3+0], cy = apos[i*3+1], cz = apos[i*3+2];
      r = make_float4(cx, cy, cz, (cx*cx + cy*cy) + cz*cz);
    } else r = make_float4(0.f, 0.f, 0.f, INFINITY);
    apk[i] = r;
  } else {
    const int j = i - NA_PAD;
    if (j < NV_PAD) {
      float4 r;
      if (j < NV) {
        const float cx = vpos[j*3+0], cy = vpos[j*3+1], cz = vpos[j*3+2];
        r = make_float4(cx, cy, cz, (cx*cx + cy*cy) + cz*cz);
      } else r = make_float4(0.f, 0.f, 0.f, INFINITY);
      vpk[j] = r;
    }
  }
}

// ---------------------------------------------------------------------------
// Batched brute-force kNN: frozen algorithm (same tiles, same ascending
// order, same `<` ballot + (d2,idx) lex insert) with 256 candidates per
// iteration. Every FP op of qq/d2 is PINNED via __fmul_rn/__fmaf_rn/
// __fadd_rn — the exact sequence the r23 on-device probe verified to
// reproduce the frozen kernel's selections bit-exactly on all 260k edges
// (and again in r24's best-first). Pinning makes the bits context-
// independent, so the 4-wide unroll cannot shift them (round 9's failure
// mode eliminated). The fminf pre-ballot only skips batches where no lane
// has d2 < thrD — in such batches no insert would occur, so selection is
// identical by construction.
// ---------------------------------------------------------------------------
#define KNN_INS(D2, JB)                                                \
  {                                                                    \
    unsigned long long m = __ballot((D2) < thrD);                      \
    if (m) {                                                           \
      do {                                                             \
        const int sl = __ffsll(m) - 1;                                 \
        m &= (m - 1ULL);                                               \
        const float v  = __shfl((D2), sl);                             \
        const int   vi = (JB) + sl;                                    \
        const bool stay = (eD < v) || (eD == v && eI < vi);            \
        const float pD = __shfl_up(eD, 1);                             \
        const int   pI = __shfl_up(eI, 1);                             \
        int pS = __shfl_up(stay ? 1 : 0, 1);                           \
        if (lane == 0) pS = 1;                                         \
        eD = stay ? eD : (pS ? v  : pD);                               \
        eI = stay ? eI : (pS ? vi : pI);                               \
      } while (m);                                                     \
      thrD = __shfl(eD, K-1);                                          \
    }                                                                  \
  }

template<int K, int NC_PAD>
__device__ __attribute__((noinline)) void knn_body(
    const float* __restrict__ qpos, const float4* __restrict__ cpk,
    int c_off, int* __restrict__ out_src, int qblock)
{
  extern __shared__ float4 tile[];
  const int tid  = threadIdx.x;
  const int wid  = tid >> 6, lane = tid & 63;
  const int q    = qblock * 8 + wid;
  const float qx = qpos[q*3+0], qy = qpos[q*3+1], qz = qpos[q*3+2];
  float qt = __fmul_rn(qx, qx);
  qt = __fmaf_rn(qy, qy, qt);
  const float qq = __fmaf_rn(qz, qz, qt);     // pinned (r23-verified seq)

  float eD = INFINITY; int eI = 0x7fffffff;   // this lane's entry of the list
  float thrD = INFINITY;                       // K-th best (broadcast)

  for (int t0 = 0; t0 < NC_PAD; t0 += KNN_TILE) {
    __syncthreads();                           // previous tile fully consumed
#pragma unroll
    for (int s = 0; s < KNN_TILE/512; ++s)
      tile[s*512 + tid] = cpk[t0 + s*512 + tid];
    __syncthreads();
#pragma unroll
    for (int it = 0; it < KNN_TILE/256; ++it) {
      const int b = it*256;
      const float4 c0 = tile[b +   0 + lane];
      const float4 c1 = tile[b +  64 + lane];
      const float4 c2 = tile[b + 128 + lane];
      const float4 c3 = tile[b + 192 + lane];
      float u0 = __fmul_rn(qx, c0.x); u0 = __fmaf_rn(qy, c0.y, u0);
      const float dot0 = __fmaf_rn(qz, c0.z, u0);
      const float d20  = __fadd_rn(__fmaf_rn(-2.0f, dot0, qq), c0.w);
      float u1 = __fmul_rn(qx, c1.x); u1 = __fmaf_rn(qy, c1.y, u1);
      const float dot1 = __fmaf_rn(qz, c1.z, u1);
      const float d21  = __fadd_rn(__fmaf_rn(-2.0f, dot1, qq), c1.w);
      float u2 = __fmul_rn(qx, c2.x); u2 = __fmaf_rn(qy, c2.y, u2);
      const float dot2 = __fmaf_rn(qz, c2.z, u2);
      const float d22  = __fadd_rn(__fmaf_rn(-2.0f, dot2, qq), c2.w);
      float u3 = __fmul_rn(qx, c3.x); u3 = __fmaf_rn(qy, c3.y, u3);
      const float dot3 = __fmaf_rn(qz, c3.z, u3);
      const float d23  = __fadd_rn(__fmaf_rn(-2.0f, dot3, qq), c3.w);
      const float dmin = fminf(fminf(d20, d21), fminf(d22, d23));
      if (__ballot(dmin < thrD)) {             // no lane qualifies -> no insert
        KNN_INS(d20, t0 + b +   0)
        KNN_INS(d21, t0 + b +  64)
        KNN_INS(d22, t0 + b + 128)
        KNN_INS(d23, t0 + b + 192)
      }
    }
  }
  if (lane < K) out_src[q*K + lane] = eI + c_off;
}

// Merged dispatcher: all three independent kNN scans co-resident.
__global__ __launch_bounds__(512) void knn_all_kernel(
    const float* __restrict__ apos, const float* __restrict__ vpos,
    const float4* __restrict__ apk, const float4* __restrict__ vpk,
    int* __restrict__ srcA, int* __restrict__ srcAV, int* __restrict__ srcVV)
{
  const int b = blockIdx.x;                   // block-uniform branch
  if (b < NA/8)
    knn_body<10, NA_PAD>(apos, apk, 0,  srcA,  b);
  else if (b < 2*(NA/8))
    knn_body<15, NV_PAD>(apos, vpk, NA, srcAV, b - NA/8);
  else
    knn_body<15, NV_PAD>(vpos, vpk, NA, srcVV, b - 2*(NA/8));
}

// ---------------------------------------------------------------------------
// LayerNorm + s/d projection, single-wave version (used by init only).
// ---------------------------------------------------------------------------
__device__ __forceinline__ void ln_sd(
    float v, int node, int lane, int l,
    const float* __restrict__ ln_g, const float* __restrict__ ln_b,
    const float* __restrict__ Ws, const float* __restrict__ Wd,
    float* __restrict__ sbuf, float* __restrict__ dbuf)
{
  const float m = wave_sum64_dpp(v) * (1.0f/64.0f);
  const float c = v - m;
  const float var = wave_sum64_dpp(c*c) * (1.0f/64.0f);
  const float hn = c * rsqrtf(var + EPS) * ln_g[l*HD + lane] + ln_b[l*HD + lane];
  const float* ws = Ws + (size_t)l*HD*HD;
  const float* wd = Wd + (size_t)l*HD*HD;
  float accs = 0.0f, accd = 0.0f;
#pragma unroll
  for (int j = 0; j < HD; ++j) {
    const float hj = __shfl(hn, j);
    accs += hj * ws[j*HD + lane];
    accd += hj * wd[j*HD + lane];
  }
  sbuf[node*HD + lane] = accs;
  dbuf[node*HD + lane] = accd;
}

// ---------------------------------------------------------------------------
// Fused first kernel: input projection + snapshot0 + LN(0) + s/d projection.
// ---------------------------------------------------------------------------
__global__ __launch_bounds__(64) void init_kernel(
    const float* __restrict__ atom_x, const float* __restrict__ vox_x,
    const float* __restrict__ Wa, const float* __restrict__ ba,
    const float* __restrict__ Wv, const float* __restrict__ bv,
    const float* __restrict__ ln_g, const float* __restrict__ ln_b,
    const float* __restrict__ Ws, const float* __restrict__ Wd,
    float* __restrict__ x, float* __restrict__ snap0,
    float* __restrict__ sbuf, float* __restrict__ dbuf)
{
  const int node = blockIdx.x;
  const int t    = threadIdx.x;
  const float* in; const float* W; const float* b;
  if (node < NA) { in = atom_x + node*FEAT;     W = Wa; b = ba; }
  else           { in = vox_x + (node-NA)*FEAT; W = Wv; b = bv; }
  float acc = b[t];
#pragma unroll
  for (int j = 0; j < FEAT; ++j) acc += in[j] * W[j*HD + t];
  x[node*HD + t] = acc;
  if (node >= NA) snap0[(node-NA)*HD + t] = acc;
  ln_sd(acc, node, t, 0, ln_g, ln_b, Ws, Wd, sbuf, dbuf);
}

// ---------------------------------------------------------------------------
// Edge attribute MLP.
// ---------------------------------------------------------------------------
__device__ __forceinline__ void load_pos(const float* ap, const float* vp,
                                         int i, float& px, float& py, float& pz)
{
  const float* p = (i < NA) ? (ap + i*3) : (vp + (i - NA)*3);
  px = p[0]; py = p[1]; pz = p[2];
}

__global__ __launch_bounds__(256) void edge_attr_kernel(
    const float* __restrict__ atom_pos, const float* __restrict__ vox_pos,
    const int* __restrict__ srcA, const int* __restrict__ srcAV,
    const int* __restrict__ srcVV,
    const float* __restrict__ w1, const float* __restrict__ b1,
    const float* __restrict__ w2, const float* __restrict__ b2,
    float* __restrict__ eattr)
{
  const int e = blockIdx.x * 256 + threadIdx.x;
  if (e >= E_TOT) return;
  int s, d, mi;
  if (e < E_AA)              { mi = 0; s = srcA[e];                 d = e / 10; }
  else if (e < E_AA + E_AV)  { mi = 1; const int t = e - E_AA;      s = srcAV[t]; d = t / 15; }
  else                       { mi = 2; const int t = e - E_AA - E_AV; s = srcVV[t]; d = NA + t / 15; }
  float sx, sy, sz, dx_, dy_, dz_;
  load_pos(atom_pos, vox_pos, s, sx, sy, sz);
  load_pos(atom_pos, vox_pos, d, dx_, dy_, dz_);
  const float ex = sx - dx_, ey = sy - dy_, ez = sz - dz_;
  const float dist = sqrtf(ex*ex + ey*ey + ez*ez);
  float acc = b2[mi];
#pragma unroll
  for (int j = 0; j < 8; ++j) {
    float h = dist * w1[mi*8 + j] + b1[mi*8 + j];
    h = (h > 0.0f) ? h : 0.0f;
    acc += h * w2[mi*8 + j];
  }
  eattr[e] = acc;
}

// ---------------------------------------------------------------------------
// Per-node attention aggregation (r16/17, passing).
// ---------------------------------------------------------------------------
template<int NE, bool IS_ATOM>
__device__ __forceinline__ float agg_node(
    int n, int lane,
    float* __restrict__ x,
    const float* __restrict__ sbuf, const float* __restrict__ dbuf,
    const float* __restrict__ eattr,
    const int* __restrict__ srcA, const int* __restrict__ srcAV,
    const int* __restrict__ srcVV,
    const float* __restrict__ We, const float* __restrict__ att, int l,
    float* __restrict__ snap)
{
  const float wet  = We[l*HD + lane];
  const float attv = att[l*HD + lane];
  const float dn   = dbuf[n*HD + lane];

  int esrc[NE]; float eat[NE];
#pragma unroll
  for (int e = 0; e < NE; ++e) {
    int src, eidx;
    if (IS_ATOM) {
      if (e < 10) { src = srcA[n*10 + e];       eidx = n*10 + e; }
      else        { src = srcAV[n*15 + (e-10)]; eidx = E_AA + n*15 + (e-10); }
    } else {
      const int nv = n - NA;
      src = srcVV[nv*15 + e]; eidx = E_AA + E_AV + nv*15 + e;
    }
    esrc[e] = src;
    eat[e]  = eattr[eidx];
  }

  float srow[NE];
#pragma unroll
  for (int e = 0; e < NE; ++e) srow[e] = sbuf[esrc[e]*HD + lane];

  float escore[NE];
#pragma unroll
  for (int e = 0; e < NE; ++e) {
    float mm = srow[e] + dn + eat[e] * wet;
    mm = (mm >= 0.0f) ? mm : 0.2f * mm;        // leaky_relu(0.2)
    escore[e] = head_sum16_dpp(mm * attv);      // reduce over d within head
  }
  float mx = -INFINITY;
#pragma unroll
  for (int e = 0; e < NE; ++e) mx = fmaxf(mx, escore[e]);
  float den = 0.0f;
#pragma unroll
  for (int e = 0; e < NE; ++e) {
    const float a = __expf(escore[e] - mx);
    escore[e] = a; den += a;
  }
  const float inv = 1.0f / den;
  float msg = 0.0f;
#pragma unroll
  for (int e = 0; e < NE; ++e) msg += (escore[e] * inv) * srow[e];
  float xv = x[n*HD + lane] + msg;
  xv = (xv > 0.0f) ? xv : 0.0f;
  x[n*HD + lane] = xv;
  if (!IS_ATOM && snap != nullptr) snap[(n - NA)*HD + lane] = xv;
  return xv;
}

// ---------------------------------------------------------------------------
// Fused layer (r17/18/21 verbatim): 4 nodes/block agg, LN(l+1) + j-sliced
// s/d projection; hn exchange transposed ([HD][4]).
// ---------------------------------------------------------------------------
__global__ __launch_bounds__(256, 4) void layer_kernel(
    float* __restrict__ x,
    const float* __restrict__ sbuf_in, float* __restrict__ dbuf,
    float* __restrict__ sbuf_out,
    const float* __restrict__ eattr,
    const int* __restrict__ srcA, const int* __restrict__ srcAV,
    const int* __restrict__ srcVV,
    const float* __restrict__ We, const float* __restrict__ att,
    const float* __restrict__ ln_g, const float* __restrict__ ln_b,
    const float* __restrict__ Ws, const float* __restrict__ Wd,
    int l, float* __restrict__ snap, int do_next)
{
  const int wid = threadIdx.x >> 6, lane = threadIdx.x & 63;
  const int n = blockIdx.x * 4 + wid;       // blocks are node-type homogeneous
  __shared__ float hn_sh[HD][4];            // transposed: [j][node]
  __shared__ float part[4][4][2][HD];

  float xv;
  if (n < NA) {
    if (!do_next) return;                    // whole block returns uniformly
    xv = agg_node<25,true>(n, lane, x, sbuf_in, dbuf, eattr,
                           srcA, srcAV, srcVV, We, att, l, nullptr);
  } else {
    xv = agg_node<15,false>(n, lane, x, sbuf_in, dbuf, eattr,
                            srcA, srcAV, srcVV, We, att, l, snap);
  }
  if (!do_next) return;

  // LayerNorm for layer l+1 (DPP wave sums)
  const int ln = l + 1;
  const float mean = wave_sum64_dpp(xv) * (1.0f/64.0f);
  const float cc   = xv - mean;
  const float var  = wave_sum64_dpp(cc*cc) * (1.0f/64.0f);
  const float hn   = cc * rsqrtf(var + EPS) * ln_g[ln*HD + lane] + ln_b[ln*HD + lane];
  hn_sh[lane][wid] = hn;
  __syncthreads();

  // j-sliced projection: wave wid covers j in [wid*16, wid*16+16) for 4 nodes
  const float* wsp = Ws + (size_t)ln*HD*HD;
  const float* wdp = Wd + (size_t)ln*HD*HD;
  float as0=0.f, as1=0.f, as2=0.f, as3=0.f;
  float ad0=0.f, ad1=0.f, ad2=0.f, ad3=0.f;
#pragma unroll
  for (int jj = 0; jj < 16; ++jj) {
    const int j = wid*16 + jj;
    const float wvs = wsp[j*HD + lane];
    const float wvd = wdp[j*HD + lane];
    const float4 h = *(const float4*)&hn_sh[j][0];   // one ds_read_b128
    as0 += h.x*wvs; ad0 += h.x*wvd;
    as1 += h.y*wvs; ad1 += h.y*wvd;
    as2 += h.z*wvs; ad2 += h.z*wvd;
    as3 += h.w*wvs; ad3 += h.w*wvd;
  }
  part[wid][0][0][lane] = as0; part[wid][0][1][lane] = ad0;
  part[wid][1][0][lane] = as1; part[wid][1][1][lane] = ad1;
  part[wid][2][0][lane] = as2; part[wid][2][1][lane] = ad2;
  part[wid][3][0][lane] = as3; part[wid][3][1][lane] = ad3;
  __syncthreads();

  const float accs = ((part[0][wid][0][lane] + part[1][wid][0][lane])
                    + (part[2][wid][0][lane] + part[3][wid][0][lane]));
  const float accd = ((part[0][wid][1][lane] + part[1][wid][1][lane])
                    + (part[2][wid][1][lane] + part[3][wid][1][lane]));
  sbuf_out[n*HD + lane] = accs;
  dbuf[n*HD + lane]     = accd;
}

// ---------------------------------------------------------------------------
// Output head: 4 vox nodes/block, j-sliced matmuls amortize weight loads 4x.
// ---------------------------------------------------------------------------
__global__ __launch_bounds__(256) void head_kernel(
    const float* __restrict__ snaps,
    const float* __restrict__ Wo1, const float* __restrict__ bo1,
    const float* __restrict__ Wo2, const float* __restrict__ bo2,
    float* __restrict__ out)
{
  const int wid = threadIdx.x >> 6, lane = threadIdx.x & 63;
  const int n = blockIdx.x * 4 + wid;
  __shared__ float cat[4][7*HD];
  __shared__ float part[4][4][HD];
  __shared__ float o1[4][HD];

#pragma unroll
  for (int c = 0; c < 7; ++c)
    cat[wid][c*HD + lane] = snaps[(size_t)c*NV*HD + n*HD + lane];
  __syncthreads();

  float a0=0.f, a1=0.f, a2=0.f, a3=0.f;
  for (int jj = 0; jj < 112; ++jj) {
    const int j = wid*112 + jj;
    const float w = Wo1[j*HD + lane];
    a0 += cat[0][j]*w; a1 += cat[1][j]*w;
    a2 += cat[2][j]*w; a3 += cat[3][j]*w;
  }
  part[wid][0][lane] = a0; part[wid][1][lane] = a1;
  part[wid][2][lane] = a2; part[wid][3][lane] = a3;
  __syncthreads();

  float acc = bo1[lane] + ((part[0][wid][lane] + part[1][wid][lane])
                         + (part[2][wid][lane] + part[3][wid][lane]));
  acc = fmaxf(acc, 0.0f);
  o1[wid][lane] = acc;
  __syncthreads();

  float b0=0.f, b1=0.f, b2=0.f, b3=0.f;
#pragma unroll
  for (int jj = 0; jj < 16; ++jj) {
    const int j = wid*16 + jj;
    const float w = Wo2[j*HD + lane];
    b0 += o1[0][j]*w; b1 += o1[1][j]*w;
    b2 += o1[2][j]*w; b3 += o1[3][j]*w;
  }
  __syncthreads();                       // part reuse
  part[wid][0][lane] = b0; part[wid][1][lane] = b1;
  part[wid][2][lane] = b2; part[wid][3][lane] = b3;
  __syncthreads();

  const float acc2 = bo2[lane] + ((part[0][wid][lane] + part[1][wid][lane])
                                + (part[2][wid][lane] + part[3][wid][lane]));
  out[n*HD + lane] = acc2;
}

__global__ __launch_bounds__(256) void copy_pos_kernel(
    const float* __restrict__ vp, float* __restrict__ out)
{
  const int i = blockIdx.x * 256 + threadIdx.x;
  if (i < NV*3) out[ENC_SIZE + i] = vp[i];
}

// ---------------------------------------------------------------------------
extern "C" void kernel_launch(void* const* d_in, const int* in_sizes, int n_in,
                              void* d_out, int out_size, void* d_ws, size_t ws_size,
                              hipStream_t stream)
{
  const float* atom_x    = (const float*)d_in[0];
  const float* atom_pos  = (const float*)d_in[1];
  const float* vox_x     = (const float*)d_in[2];
  const float* vox_pos   = (const float*)d_in[3];
  const float* W_atom_in = (const float*)d_in[4];
  const float* b_atom_in = (const float*)d_in[5];
  const float* W_vox_in  = (const float*)d_in[6];
  const float* b_vox_in  = (const float*)d_in[7];
  const float* emlp_w1   = (const float*)d_in[8];
  const float* emlp_b1   = (const float*)d_in[9];
  const float* emlp_w2   = (const float*)d_in[10];
  const float* emlp_b2   = (const float*)d_in[11];
  const float* ln_g      = (const float*)d_in[12];
  const float* ln_b      = (const float*)d_in[13];
  const float* Ws        = (const float*)d_in[14];
  const float* Wd        = (const float*)d_in[15];
  const float* We        = (const float*)d_in[16];
  const float* att       = (const float*)d_in[17];
  const float* Wo1       = (const float*)d_in[18];
  const float* bo1       = (const float*)d_in[19];
  const float* Wo2       = (const float*)d_in[20];
  const float* bo2       = (const float*)d_in[21];
  float* out = (float*)d_out;

  // workspace layout (floats), ~21.8 MB
  float* ws    = (float*)d_ws;
  float* x     = ws;                          // [NN][HD]
  float* sA    = x  + (size_t)NN*HD;          // [NN][HD] sbuf ping
  float* sB    = sA + (size_t)NN*HD;          // [NN][HD] sbuf pong
  float* dbuf  = sB + (size_t)NN*HD;          // [NN][HD]
  float* eattr = dbuf + (size_t)NN*HD;        // [E_TOT]
  float* snaps = eattr + E_TOT;               // [7][NV][HD]
  int*   srcA  = (int*)(snaps + (size_t)7*NV*HD);
  int*   srcAV = srcA  + E_AA;
  int*   srcVV = srcAV + E_AV;
  float4* apk  = (float4*)(srcVV + E_VV);     // [NA_PAD] packed atoms
  float4* vpk  = apk + NA_PAD;                // [NV_PAD] packed voxels

  // 1. pack candidates, then merged batched kNN (all three scans co-resident)
  pack_kernel<<<(NA_PAD + NV_PAD + 255)/256, 256, 0, stream>>>(
      atom_pos, vox_pos, apk, vpk);
  knn_all_kernel<<<NA/8 + NA/8 + NV/8, 512, KNN_TILE*sizeof(float4), stream>>>(
      atom_pos, vox_pos, apk, vpk, srcA, srcAV, srcVV);
  // 2. edge attributes
  edge_attr_kernel<<<(E_TOT + 255)/256, 256, 0, stream>>>(
      atom_pos, vox_pos, srcA, srcAV, srcVV,
      emlp_w1, emlp_b1, emlp_w2, emlp_b2, eattr);
  // 3. fused input proj + LN0 + s/d proj
  init_kernel<<<NN, 64, 0, stream>>>(atom_x, vox_x, W_atom_in, b_atom_in,
                                     W_vox_in, b_vox_in, ln_g, ln_b, Ws, Wd,
                                     x, snaps, sA, dbuf);
  // 4. 12 fused GAT layers (per-layer dispatch keeps L2 warm across layers)
  for (int l = 0; l < NLAYER; ++l) {
    float* s_in  = (l & 1) ? sB : sA;
    float* s_out = (l & 1) ? sA : sB;
    float* snap  = (l & 1) ? (snaps + (size_t)(l/2 + 1)*NV*HD) : nullptr;
    layer_kernel<<<NGRP, 256, 0, stream>>>(x, s_in, dbuf, s_out, eattr,
                                           srcA, srcAV, srcVV, We, att,
                                           ln_g, ln_b, Ws, Wd, l, snap,
                                           (l < NLAYER-1) ? 1 : 0);
  }
  // 5. output head + vox_pos passthrough
  head_kernel<<<NV/4, 256, 0, stream>>>(snaps, Wo1, bo1, Wo2, bo2, out);
  copy_pos_kernel<<<(NV*3 + 255)/256, 256, 0, stream>>>(vox_pos, out);
}

// Round 27
// 346.245 us; speedup vs baseline: 1.5766x; 1.1327x over previous
//
#include <hip/hip_runtime.h>
#include <math.h>

#define NA 8000
#define NV 4000
#define NN 12000
#define NA_PAD 8192
#define NV_PAD 4096
#define KNN_TILE 2048
#define FEAT 32
#define HD 64
#define NLAYER 12
#define E_AA 80000
#define E_AV 120000
#define E_VV 60000
#define E_TOT 260000
#define ENC_SIZE (NV * HD)
#define EPS 1e-5f
#define NGRP (NN/4)

__device__ __forceinline__ float wave_sum64(float v) {
#pragma unroll
  for (int off = 1; off < 64; off <<= 1) v += __shfl_xor(v, off);
  return v;
}

// DPP butterfly helpers: pure VALU (v_add_f32_dpp), no DS pipe.
__device__ __forceinline__ float dpp_step(float v, const int ctrl) {
  int p;
  switch (ctrl) {
    case 0xB1:  p = __builtin_amdgcn_update_dpp(0, __float_as_int(v), 0xB1,  0xF, 0xF, true); break;
    case 0x4E:  p = __builtin_amdgcn_update_dpp(0, __float_as_int(v), 0x4E,  0xF, 0xF, true); break;
    case 0x141: p = __builtin_amdgcn_update_dpp(0, __float_as_int(v), 0x141, 0xF, 0xF, true); break;
    default:    p = __builtin_amdgcn_update_dpp(0, __float_as_int(v), 0x140, 0xF, 0xF, true); break;
  }
  return v + __int_as_float(p);
}

__device__ __forceinline__ float head_sum16_dpp(float v) {
  v = dpp_step(v, 0xB1);
  v = dpp_step(v, 0x4E);
  v = dpp_step(v, 0x141);
  v = dpp_step(v, 0x140);
  return v;
}

__device__ __forceinline__ float wave_sum64_dpp(float v) {
  v = head_sum16_dpp(v);
  v += __shfl_xor(v, 16);
  v += __shfl_xor(v, 32);
  return v;
}

// DPP wave_shr:1 (ctrl 0x138, gfx9 family): lane i reads lane i-1, lane 0
// reads 0 (bound_ctrl). Pure-VALU replacement for __shfl_up(x,1) in the
// insert loop — lane 0's shifted values are dead there (pS forced to 1).
__device__ __forceinline__ float dpp_shr1_f(float v) {
  const int p = __builtin_amdgcn_update_dpp(0, __float_as_int(v), 0x138, 0xF, 0xF, true);
  return __int_as_float(p);
}
__device__ __forceinline__ int dpp_shr1_i(int v) {
  return __builtin_amdgcn_update_dpp(0, v, 0x138, 0xF, 0xF, true);
}

// ---------------------------------------------------------------------------
// Pack candidate positions as [x, y, z, |c|^2] float4, padded with cc=+INF.
// (FROZEN)
// ---------------------------------------------------------------------------
__global__ __launch_bounds__(256) void pack_kernel(
    const float* __restrict__ apos, const float* __restrict__ vpos,
    float4* __restrict__ apk, float4* __restrict__ vpk)
{
  const int i = blockIdx.x * 256 + threadIdx.x;
  if (i < NA_PAD) {
    float4 r;
    if (i < NA) {
      const float cx = apos[i*3+0], cy = apos[i*3+1], cz = apos[i*3+2];
      r = make_float4(cx, cy, cz, (cx*cx + cy*cy) + cz*cz);
    } else r = make_float4(0.f, 0.f, 0.f, INFINITY);
    apk[i] = r;
  } else {
    const int j = i - NA_PAD;
    if (j < NV_PAD) {
      float4 r;
      if (j < NV) {
        const float cx = vpos[j*3+0], cy = vpos[j*3+1], cz = vpos[j*3+2];
        r = make_float4(cx, cy, cz, (cx*cx + cy*cy) + cz*cz);
      } else r = make_float4(0.f, 0.f, 0.f, INFINITY);
      vpk[j] = r;
    }
  }
}

// ---------------------------------------------------------------------------
// Batched brute-force kNN (r26, passing): frozen algorithm with 256
// candidates/iteration, every FP op pinned (r23 probe: bit-identical
// selections). r27 change: the insert loop's three __shfl_up (ds_bpermute,
// DS pipe) are replaced by DPP wave_shr:1 (pure VALU) — data movement
// identical (lane-0 shifted values are dead: pS forced to 1), no FP change.
// ---------------------------------------------------------------------------
#define KNN_INS(D2, JB)                                                \
  {                                                                    \
    unsigned long long m = __ballot((D2) < thrD);                      \
    if (m) {                                                           \
      do {                                                             \
        const int sl = __ffsll(m) - 1;                                 \
        m &= (m - 1ULL);                                               \
        const float v  = __shfl((D2), sl);                             \
        const int   vi = (JB) + sl;                                    \
        const bool stay = (eD < v) || (eD == v && eI < vi);            \
        const float pD = dpp_shr1_f(eD);                               \
        const int   pI = dpp_shr1_i(eI);                               \
        int pS = dpp_shr1_i(stay ? 1 : 0);                             \
        if (lane == 0) pS = 1;                                         \
        eD = stay ? eD : (pS ? v  : pD);                               \
        eI = stay ? eI : (pS ? vi : pI);                               \
      } while (m);                                                     \
      thrD = __shfl(eD, K-1);                                          \
    }                                                                  \
  }

template<int K, int NC_PAD>
__device__ __attribute__((noinline)) void knn_body(
    const float* __restrict__ qpos, const float4* __restrict__ cpk,
    int c_off, int* __restrict__ out_src, int qblock)
{
  extern __shared__ float4 tile[];
  const int tid  = threadIdx.x;
  const int wid  = tid >> 6, lane = tid & 63;
  const int q    = qblock * 8 + wid;
  const float qx = qpos[q*3+0], qy = qpos[q*3+1], qz = qpos[q*3+2];
  float qt = __fmul_rn(qx, qx);
  qt = __fmaf_rn(qy, qy, qt);
  const float qq = __fmaf_rn(qz, qz, qt);     // pinned (r23-verified seq)

  float eD = INFINITY; int eI = 0x7fffffff;   // this lane's entry of the list
  float thrD = INFINITY;                       // K-th best (broadcast)

  for (int t0 = 0; t0 < NC_PAD; t0 += KNN_TILE) {
    __syncthreads();                           // previous tile fully consumed
#pragma unroll
    for (int s = 0; s < KNN_TILE/512; ++s)
      tile[s*512 + tid] = cpk[t0 + s*512 + tid];
    __syncthreads();
#pragma unroll
    for (int it = 0; it < KNN_TILE/256; ++it) {
      const int b = it*256;
      const float4 c0 = tile[b +   0 + lane];
      const float4 c1 = tile[b +  64 + lane];
      const float4 c2 = tile[b + 128 + lane];
      const float4 c3 = tile[b + 192 + lane];
      float u0 = __fmul_rn(qx, c0.x); u0 = __fmaf_rn(qy, c0.y, u0);
      const float dot0 = __fmaf_rn(qz, c0.z, u0);
      const float d20  = __fadd_rn(__fmaf_rn(-2.0f, dot0, qq), c0.w);
      float u1 = __fmul_rn(qx, c1.x); u1 = __fmaf_rn(qy, c1.y, u1);
      const float dot1 = __fmaf_rn(qz, c1.z, u1);
      const float d21  = __fadd_rn(__fmaf_rn(-2.0f, dot1, qq), c1.w);
      float u2 = __fmul_rn(qx, c2.x); u2 = __fmaf_rn(qy, c2.y, u2);
      const float dot2 = __fmaf_rn(qz, c2.z, u2);
      const float d22  = __fadd_rn(__fmaf_rn(-2.0f, dot2, qq), c2.w);
      float u3 = __fmul_rn(qx, c3.x); u3 = __fmaf_rn(qy, c3.y, u3);
      const float dot3 = __fmaf_rn(qz, c3.z, u3);
      const float d23  = __fadd_rn(__fmaf_rn(-2.0f, dot3, qq), c3.w);
      const float dmin = fminf(fminf(d20, d21), fminf(d22, d23));
      if (__ballot(dmin < thrD)) {             // no lane qualifies -> no insert
        KNN_INS(d20, t0 + b +   0)
        KNN_INS(d21, t0 + b +  64)
        KNN_INS(d22, t0 + b + 128)
        KNN_INS(d23, t0 + b + 192)
      }
    }
  }
  if (lane < K) out_src[q*K + lane] = eI + c_off;
}

// Merged dispatcher: all three independent kNN scans co-resident.
__global__ __launch_bounds__(512) void knn_all_kernel(
    const float* __restrict__ apos, const float* __restrict__ vpos,
    const float4* __restrict__ apk, const float4* __restrict__ vpk,
    int* __restrict__ srcA, int* __restrict__ srcAV, int* __restrict__ srcVV)
{
  const int b = blockIdx.x;                   // block-uniform branch
  if (b < NA/8)
    knn_body<10, NA_PAD>(apos, apk, 0,  srcA,  b);
  else if (b < 2*(NA/8))
    knn_body<15, NV_PAD>(apos, vpk, NA, srcAV, b - NA/8);
  else
    knn_body<15, NV_PAD>(vpos, vpk, NA, srcVV, b - 2*(NA/8));
}

// ---------------------------------------------------------------------------
// LayerNorm + s/d projection, single-wave version (used by init only).
// ---------------------------------------------------------------------------
__device__ __forceinline__ void ln_sd(
    float v, int node, int lane, int l,
    const float* __restrict__ ln_g, const float* __restrict__ ln_b,
    const float* __restrict__ Ws, const float* __restrict__ Wd,
    float* __restrict__ sbuf, float* __restrict__ dbuf)
{
  const float m = wave_sum64_dpp(v) * (1.0f/64.0f);
  const float c = v - m;
  const float var = wave_sum64_dpp(c*c) * (1.0f/64.0f);
  const float hn = c * rsqrtf(var + EPS) * ln_g[l*HD + lane] + ln_b[l*HD + lane];
  const float* ws = Ws + (size_t)l*HD*HD;
  const float* wd = Wd + (size_t)l*HD*HD;
  float accs = 0.0f, accd = 0.0f;
#pragma unroll
  for (int j = 0; j < HD; ++j) {
    const float hj = __shfl(hn, j);
    accs += hj * ws[j*HD + lane];
    accd += hj * wd[j*HD + lane];
  }
  sbuf[node*HD + lane] = accs;
  dbuf[node*HD + lane] = accd;
}

// ---------------------------------------------------------------------------
// Fused first kernel: input projection + snapshot0 + LN(0) + s/d projection.
// ---------------------------------------------------------------------------
__global__ __launch_bounds__(64) void init_kernel(
    const float* __restrict__ atom_x, const float* __restrict__ vox_x,
    const float* __restrict__ Wa, const float* __restrict__ ba,
    const float* __restrict__ Wv, const float* __restrict__ bv,
    const float* __restrict__ ln_g, const float* __restrict__ ln_b,
    const float* __restrict__ Ws, const float* __restrict__ Wd,
    float* __restrict__ x, float* __restrict__ snap0,
    float* __restrict__ sbuf, float* __restrict__ dbuf)
{
  const int node = blockIdx.x;
  const int t    = threadIdx.x;
  const float* in; const float* W; const float* b;
  if (node < NA) { in = atom_x + node*FEAT;     W = Wa; b = ba; }
  else           { in = vox_x + (node-NA)*FEAT; W = Wv; b = bv; }
  float acc = b[t];
#pragma unroll
  for (int j = 0; j < FEAT; ++j) acc += in[j] * W[j*HD + t];
  x[node*HD + t] = acc;
  if (node >= NA) snap0[(node-NA)*HD + t] = acc;
  ln_sd(acc, node, t, 0, ln_g, ln_b, Ws, Wd, sbuf, dbuf);
}

// ---------------------------------------------------------------------------
// Edge attribute MLP.
// ---------------------------------------------------------------------------
__device__ __forceinline__ void load_pos(const float* ap, const float* vp,
                                         int i, float& px, float& py, float& pz)
{
  const float* p = (i < NA) ? (ap + i*3) : (vp + (i - NA)*3);
  px = p[0]; py = p[1]; pz = p[2];
}

__global__ __launch_bounds__(256) void edge_attr_kernel(
    const float* __restrict__ atom_pos, const float* __restrict__ vox_pos,
    const int* __restrict__ srcA, const int* __restrict__ srcAV,
    const int* __restrict__ srcVV,
    const float* __restrict__ w1, const float* __restrict__ b1,
    const float* __restrict__ w2, const float* __restrict__ b2,
    float* __restrict__ eattr)
{
  const int e = blockIdx.x * 256 + threadIdx.x;
  if (e >= E_TOT) return;
  int s, d, mi;
  if (e < E_AA)              { mi = 0; s = srcA[e];                 d = e / 10; }
  else if (e < E_AA + E_AV)  { mi = 1; const int t = e - E_AA;      s = srcAV[t]; d = t / 15; }
  else                       { mi = 2; const int t = e - E_AA - E_AV; s = srcVV[t]; d = NA + t / 15; }
  float sx, sy, sz, dx_, dy_, dz_;
  load_pos(atom_pos, vox_pos, s, sx, sy, sz);
  load_pos(atom_pos, vox_pos, d, dx_, dy_, dz_);
  const float ex = sx - dx_, ey = sy - dy_, ez = sz - dz_;
  const float dist = sqrtf(ex*ex + ey*ey + ez*ez);
  float acc = b2[mi];
#pragma unroll
  for (int j = 0; j < 8; ++j) {
    float h = dist * w1[mi*8 + j] + b1[mi*8 + j];
    h = (h > 0.0f) ? h : 0.0f;
    acc += h * w2[mi*8 + j];
  }
  eattr[e] = acc;
}

// ---------------------------------------------------------------------------
// Per-node attention aggregation (r16/17, passing).
// ---------------------------------------------------------------------------
template<int NE, bool IS_ATOM>
__device__ __forceinline__ float agg_node(
    int n, int lane,
    float* __restrict__ x,
    const float* __restrict__ sbuf, const float* __restrict__ dbuf,
    const float* __restrict__ eattr,
    const int* __restrict__ srcA, const int* __restrict__ srcAV,
    const int* __restrict__ srcVV,
    const float* __restrict__ We, const float* __restrict__ att, int l,
    float* __restrict__ snap)
{
  const float wet  = We[l*HD + lane];
  const float attv = att[l*HD + lane];
  const float dn   = dbuf[n*HD + lane];

  int esrc[NE]; float eat[NE];
#pragma unroll
  for (int e = 0; e < NE; ++e) {
    int src, eidx;
    if (IS_ATOM) {
      if (e < 10) { src = srcA[n*10 + e];       eidx = n*10 + e; }
      else        { src = srcAV[n*15 + (e-10)]; eidx = E_AA + n*15 + (e-10); }
    } else {
      const int nv = n - NA;
      src = srcVV[nv*15 + e]; eidx = E_AA + E_AV + nv*15 + e;
    }
    esrc[e] = src;
    eat[e]  = eattr[eidx];
  }

  float srow[NE];
#pragma unroll
  for (int e = 0; e < NE; ++e) srow[e] = sbuf[esrc[e]*HD + lane];

  float escore[NE];
#pragma unroll
  for (int e = 0; e < NE; ++e) {
    float mm = srow[e] + dn + eat[e] * wet;
    mm = (mm >= 0.0f) ? mm : 0.2f * mm;        // leaky_relu(0.2)
    escore[e] = head_sum16_dpp(mm * attv);      // reduce over d within head
  }
  float mx = -INFINITY;
#pragma unroll
  for (int e = 0; e < NE; ++e) mx = fmaxf(mx, escore[e]);
  float den = 0.0f;
#pragma unroll
  for (int e = 0; e < NE; ++e) {
    const float a = __expf(escore[e] - mx);
    escore[e] = a; den += a;
  }
  const float inv = 1.0f / den;
  float msg = 0.0f;
#pragma unroll
  for (int e = 0; e < NE; ++e) msg += (escore[e] * inv) * srow[e];
  float xv = x[n*HD + lane] + msg;
  xv = (xv > 0.0f) ? xv : 0.0f;
  x[n*HD + lane] = xv;
  if (!IS_ATOM && snap != nullptr) snap[(n - NA)*HD + lane] = xv;
  return xv;
}

// ---------------------------------------------------------------------------
// Fused layer (r17/18/21 verbatim): 4 nodes/block agg, LN(l+1) + j-sliced
// s/d projection; hn exchange transposed ([HD][4]).
// ---------------------------------------------------------------------------
__global__ __launch_bounds__(256, 4) void layer_kernel(
    float* __restrict__ x,
    const float* __restrict__ sbuf_in, float* __restrict__ dbuf,
    float* __restrict__ sbuf_out,
    const float* __restrict__ eattr,
    const int* __restrict__ srcA, const int* __restrict__ srcAV,
    const int* __restrict__ srcVV,
    const float* __restrict__ We, const float* __restrict__ att,
    const float* __restrict__ ln_g, const float* __restrict__ ln_b,
    const float* __restrict__ Ws, const float* __restrict__ Wd,
    int l, float* __restrict__ snap, int do_next)
{
  const int wid = threadIdx.x >> 6, lane = threadIdx.x & 63;
  const int n = blockIdx.x * 4 + wid;       // blocks are node-type homogeneous
  __shared__ float hn_sh[HD][4];            // transposed: [j][node]
  __shared__ float part[4][4][2][HD];

  float xv;
  if (n < NA) {
    if (!do_next) return;                    // whole block returns uniformly
    xv = agg_node<25,true>(n, lane, x, sbuf_in, dbuf, eattr,
                           srcA, srcAV, srcVV, We, att, l, nullptr);
  } else {
    xv = agg_node<15,false>(n, lane, x, sbuf_in, dbuf, eattr,
                            srcA, srcAV, srcVV, We, att, l, snap);
  }
  if (!do_next) return;

  // LayerNorm for layer l+1 (DPP wave sums)
  const int ln = l + 1;
  const float mean = wave_sum64_dpp(xv) * (1.0f/64.0f);
  const float cc   = xv - mean;
  const float var  = wave_sum64_dpp(cc*cc) * (1.0f/64.0f);
  const float hn   = cc * rsqrtf(var + EPS) * ln_g[ln*HD + lane] + ln_b[ln*HD + lane];
  hn_sh[lane][wid] = hn;
  __syncthreads();

  // j-sliced projection: wave wid covers j in [wid*16, wid*16+16) for 4 nodes
  const float* wsp = Ws + (size_t)ln*HD*HD;
  const float* wdp = Wd + (size_t)ln*HD*HD;
  float as0=0.f, as1=0.f, as2=0.f, as3=0.f;
  float ad0=0.f, ad1=0.f, ad2=0.f, ad3=0.f;
#pragma unroll
  for (int jj = 0; jj < 16; ++jj) {
    const int j = wid*16 + jj;
    const float wvs = wsp[j*HD + lane];
    const float wvd = wdp[j*HD + lane];
    const float4 h = *(const float4*)&hn_sh[j][0];   // one ds_read_b128
    as0 += h.x*wvs; ad0 += h.x*wvd;
    as1 += h.y*wvs; ad1 += h.y*wvd;
    as2 += h.z*wvs; ad2 += h.z*wvd;
    as3 += h.w*wvs; ad3 += h.w*wvd;
  }
  part[wid][0][0][lane] = as0; part[wid][0][1][lane] = ad0;
  part[wid][1][0][lane] = as1; part[wid][1][1][lane] = ad1;
  part[wid][2][0][lane] = as2; part[wid][2][1][lane] = ad2;
  part[wid][3][0][lane] = as3; part[wid][3][1][lane] = ad3;
  __syncthreads();

  const float accs = ((part[0][wid][0][lane] + part[1][wid][0][lane])
                    + (part[2][wid][0][lane] + part[3][wid][0][lane]));
  const float accd = ((part[0][wid][1][lane] + part[1][wid][1][lane])
                    + (part[2][wid][1][lane] + part[3][wid][1][lane]));
  sbuf_out[n*HD + lane] = accs;
  dbuf[n*HD + lane]     = accd;
}

// ---------------------------------------------------------------------------
// Output head: 4 vox nodes/block, j-sliced matmuls amortize weight loads 4x.
// ---------------------------------------------------------------------------
__global__ __launch_bounds__(256) void head_kernel(
    const float* __restrict__ snaps,
    const float* __restrict__ Wo1, const float* __restrict__ bo1,
    const float* __restrict__ Wo2, const float* __restrict__ bo2,
    float* __restrict__ out)
{
  const int wid = threadIdx.x >> 6, lane = threadIdx.x & 63;
  const int n = blockIdx.x * 4 + wid;
  __shared__ float cat[4][7*HD];
  __shared__ float part[4][4][HD];
  __shared__ float o1[4][HD];

#pragma unroll
  for (int c = 0; c < 7; ++c)
    cat[wid][c*HD + lane] = snaps[(size_t)c*NV*HD + n*HD + lane];
  __syncthreads();

  float a0=0.f, a1=0.f, a2=0.f, a3=0.f;
  for (int jj = 0; jj < 112; ++jj) {
    const int j = wid*112 + jj;
    const float w = Wo1[j*HD + lane];
    a0 += cat[0][j]*w; a1 += cat[1][j]*w;
    a2 += cat[2][j]*w; a3 += cat[3][j]*w;
  }
  part[wid][0][lane] = a0; part[wid][1][lane] = a1;
  part[wid][2][lane] = a2; part[wid][3][lane] = a3;
  __syncthreads();

  float acc = bo1[lane] + ((part[0][wid][lane] + part[1][wid][lane])
                         + (part[2][wid][lane] + part[3][wid][lane]));
  acc = fmaxf(acc, 0.0f);
  o1[wid][lane] = acc;
  __syncthreads();

  float b0=0.f, b1=0.f, b2=0.f, b3=0.f;
#pragma unroll
  for (int jj = 0; jj < 16; ++jj) {
    const int j = wid*16 + jj;
    const float w = Wo2[j*HD + lane];
    b0 += o1[0][j]*w; b1 += o1[1][j]*w;
    b2 += o1[2][j]*w; b3 += o1[3][j]*w;
  }
  __syncthreads();                       // part reuse
  part[wid][0][lane] = b0; part[wid][1][lane] = b1;
  part[wid][2][lane] = b2; part[wid][3][lane] = b3;
  __syncthreads();

  const float acc2 = bo2[lane] + ((part[0][wid][lane] + part[1][wid][lane])
                                + (part[2][wid][lane] + part[3][wid][lane]));
  out[n*HD + lane] = acc2;
}

__global__ __launch_bounds__(256) void copy_pos_kernel(
    const float* __restrict__ vp, float* __restrict__ out)
{
  const int i = blockIdx.x * 256 + threadIdx.x;
  if (i < NV*3) out[ENC_SIZE + i] = vp[i];
}

// ---------------------------------------------------------------------------
extern "C" void kernel_launch(void* const* d_in, const int* in_sizes, int n_in,
                              void* d_out, int out_size, void* d_ws, size_t ws_size,
                              hipStream_t stream)
{
  const float* atom_x    = (const float*)d_in[0];
  const float* atom_pos  = (const float*)d_in[1];
  const float* vox_x     = (const float*)d_in[2];
  const float* vox_pos   = (const float*)d_in[3];
  const float* W_atom_in = (const float*)d_in[4];
  const float* b_atom_in = (const float*)d_in[5];
  const float* W_vox_in  = (const float*)d_in[6];
  const float* b_vox_in  = (const float*)d_in[7];
  const float* emlp_w1   = (const float*)d_in[8];
  const float* emlp_b1   = (const float*)d_in[9];
  const float* emlp_w2   = (const float*)d_in[10];
  const float* emlp_b2   = (const float*)d_in[11];
  const float* ln_g      = (const float*)d_in[12];
  const float* ln_b      = (const float*)d_in[13];
  const float* Ws        = (const float*)d_in[14];
  const float* Wd        = (const float*)d_in[15];
  const float* We        = (const float*)d_in[16];
  const float* att       = (const float*)d_in[17];
  const float* Wo1       = (const float*)d_in[18];
  const float* bo1       = (const float*)d_in[19];
  const float* Wo2       = (const float*)d_in[20];
  const float* bo2       = (const float*)d_in[21];
  float* out = (float*)d_out;

  // workspace layout (floats), ~21.8 MB
  float* ws    = (float*)d_ws;
  float* x     = ws;                          // [NN][HD]
  float* sA    = x  + (size_t)NN*HD;          // [NN][HD] sbuf ping
  float* sB    = sA + (size_t)NN*HD;          // [NN][HD] sbuf pong
  float* dbuf  = sB + (size_t)NN*HD;          // [NN][HD]
  float* eattr = dbuf + (size_t)NN*HD;        // [E_TOT]
  float* snaps = eattr + E_TOT;               // [7][NV][HD]
  int*   srcA  = (int*)(snaps + (size_t)7*NV*HD);
  int*   srcAV = srcA  + E_AA;
  int*   srcVV = srcAV + E_AV;
  float4* apk  = (float4*)(srcVV + E_VV);     // [NA_PAD] packed atoms
  float4* vpk  = apk + NA_PAD;                // [NV_PAD] packed voxels

  // 1. pack candidates, then merged batched kNN (all three scans co-resident)
  pack_kernel<<<(NA_PAD + NV_PAD + 255)/256, 256, 0, stream>>>(
      atom_pos, vox_pos, apk, vpk);
  knn_all_kernel<<<NA/8 + NA/8 + NV/8, 512, KNN_TILE*sizeof(float4), stream>>>(
      atom_pos, vox_pos, apk, vpk, srcA, srcAV, srcVV);
  // 2. edge attributes
  edge_attr_kernel<<<(E_TOT + 255)/256, 256, 0, stream>>>(
      atom_pos, vox_pos, srcA, srcAV, srcVV,
      emlp_w1, emlp_b1, emlp_w2, emlp_b2, eattr);
  // 3. fused input proj + LN0 + s/d proj
  init_kernel<<<NN, 64, 0, stream>>>(atom_x, vox_x, W_atom_in, b_atom_in,
                                     W_vox_in, b_vox_in, ln_g, ln_b, Ws, Wd,
                                     x, snaps, sA, dbuf);
  // 4. 12 fused GAT layers (per-layer dispatch keeps L2 warm across layers)
  for (int l = 0; l < NLAYER; ++l) {
    float* s_in  = (l & 1) ? sB : sA;
    float* s_out = (l & 1) ? sA : sB;
    float* snap  = (l & 1) ? (snaps + (size_t)(l/2 + 1)*NV*HD) : nullptr;
    layer_kernel<<<NGRP, 256, 0, stream>>>(x, s_in, dbuf, s_out, eattr,
                                           srcA, srcAV, srcVV, We, att,
                                           ln_g, ln_b, Ws, Wd, l, snap,
                                           (l < NLAYER-1) ? 1 : 0);
  }
  // 5. output head + vox_pos passthrough
  head_kernel<<<NV/4, 256, 0, stream>>>(snaps, Wo1, bo1, Wo2, bo2, out);
  copy_pos_kernel<<<(NV*3 + 255)/256, 256, 0, stream>>>(vox_pos, out);
}

// Round 28
// 334.299 us; speedup vs baseline: 1.6329x; 1.0357x over previous
//
#include <hip/hip_runtime.h>
#include <math.h>

#define NA 8000
#define NV 4000
#define NN 12000
#define NA_PAD 8192
#define NV_PAD 4096
#define KNN_TILE 1024
#define FEAT 32
#define HD 64
#define NLAYER 12
#define E_AA 80000
#define E_AV 120000
#define E_VV 60000
#define E_TOT 260000
#define ENC_SIZE (NV * HD)
#define EPS 1e-5f
#define NGRP (NN/4)
#define KNN_BLOCKS (NA/8 + NA/8 + NV/8)   // 2500
#define INIT_BLOCKS (NN/8)                 // 1500

__device__ __forceinline__ float wave_sum64(float v) {
#pragma unroll
  for (int off = 1; off < 64; off <<= 1) v += __shfl_xor(v, off);
  return v;
}

// DPP butterfly helpers: pure VALU (v_add_f32_dpp), no DS pipe.
__device__ __forceinline__ float dpp_step(float v, const int ctrl) {
  int p;
  switch (ctrl) {
    case 0xB1:  p = __builtin_amdgcn_update_dpp(0, __float_as_int(v), 0xB1,  0xF, 0xF, true); break;
    case 0x4E:  p = __builtin_amdgcn_update_dpp(0, __float_as_int(v), 0x4E,  0xF, 0xF, true); break;
    case 0x141: p = __builtin_amdgcn_update_dpp(0, __float_as_int(v), 0x141, 0xF, 0xF, true); break;
    default:    p = __builtin_amdgcn_update_dpp(0, __float_as_int(v), 0x140, 0xF, 0xF, true); break;
  }
  return v + __int_as_float(p);
}

__device__ __forceinline__ float head_sum16_dpp(float v) {
  v = dpp_step(v, 0xB1);
  v = dpp_step(v, 0x4E);
  v = dpp_step(v, 0x141);
  v = dpp_step(v, 0x140);
  return v;
}

__device__ __forceinline__ float wave_sum64_dpp(float v) {
  v = head_sum16_dpp(v);
  v += __shfl_xor(v, 16);
  v += __shfl_xor(v, 32);
  return v;
}

// DPP wave_shr:1 (ctrl 0x138): pure-VALU __shfl_up(x,1); lane-0 shifted
// values are dead in the insert (pS forced to 1). (r27, passing)
__device__ __forceinline__ float dpp_shr1_f(float v) {
  const int p = __builtin_amdgcn_update_dpp(0, __float_as_int(v), 0x138, 0xF, 0xF, true);
  return __int_as_float(p);
}
__device__ __forceinline__ int dpp_shr1_i(int v) {
  return __builtin_amdgcn_update_dpp(0, v, 0x138, 0xF, 0xF, true);
}

// ---------------------------------------------------------------------------
// Pack candidate positions as [x, y, z, |c|^2] float4, padded with cc=+INF.
// (FROZEN)
// ---------------------------------------------------------------------------
__global__ __launch_bounds__(256) void pack_kernel(
    const float* __restrict__ apos, const float* __restrict__ vpos,
    float4* __restrict__ apk, float4* __restrict__ vpk)
{
  const int i = blockIdx.x * 256 + threadIdx.x;
  if (i < NA_PAD) {
    float4 r;
    if (i < NA) {
      const float cx = apos[i*3+0], cy = apos[i*3+1], cz = apos[i*3+2];
      r = make_float4(cx, cy, cz, (cx*cx + cy*cy) + cz*cz);
    } else r = make_float4(0.f, 0.f, 0.f, INFINITY);
    apk[i] = r;
  } else {
    const int j = i - NA_PAD;
    if (j < NV_PAD) {
      float4 r;
      if (j < NV) {
        const float cx = vpos[j*3+0], cy = vpos[j*3+1], cz = vpos[j*3+2];
        r = make_float4(cx, cy, cz, (cx*cx + cy*cy) + cz*cz);
      } else r = make_float4(0.f, 0.f, 0.f, INFINITY);
      vpk[j] = r;
    }
  }
}

// ---------------------------------------------------------------------------
// Batched brute-force kNN (r26/r27, passing) + DOUBLE-BUFFERED staging
// (r13's passing structure: 2x1024 buffers, same 32KB LDS; next-tile loads
// issued before processing current, one barrier per tile). Order preserved,
// d2 bits pinned (context-independent, r23-probe-verified + r26/r27).
// ---------------------------------------------------------------------------
#define KNN_INS(D2, JB)                                                \
  {                                                                    \
    unsigned long long m = __ballot((D2) < thrD);                      \
    if (m) {                                                           \
      do {                                                             \
        const int sl = __ffsll(m) - 1;                                 \
        m &= (m - 1ULL);                                               \
        const float v  = __shfl((D2), sl);                             \
        const int   vi = (JB) + sl;                                    \
        const bool stay = (eD < v) || (eD == v && eI < vi);            \
        const float pD = dpp_shr1_f(eD);                               \
        const int   pI = dpp_shr1_i(eI);                               \
        int pS = dpp_shr1_i(stay ? 1 : 0);                             \
        if (lane == 0) pS = 1;                                         \
        eD = stay ? eD : (pS ? v  : pD);                               \
        eI = stay ? eI : (pS ? vi : pI);                               \
      } while (m);                                                     \
      thrD = __shfl(eD, K-1);                                          \
    }                                                                  \
  }

template<int K, int NC_PAD>
__device__ __attribute__((noinline)) void knn_body(
    const float* __restrict__ qpos, const float4* __restrict__ cpk,
    int c_off, int* __restrict__ out_src, int qblock)
{
  extern __shared__ float4 tile[];            // [2][KNN_TILE]
  const int tid  = threadIdx.x;
  const int wid  = tid >> 6, lane = tid & 63;
  const int q    = qblock * 8 + wid;
  const float qx = qpos[q*3+0], qy = qpos[q*3+1], qz = qpos[q*3+2];
  float qt = __fmul_rn(qx, qx);
  qt = __fmaf_rn(qy, qy, qt);
  const float qq = __fmaf_rn(qz, qz, qt);     // pinned (r23-verified seq)

  float eD = INFINITY; int eI = 0x7fffffff;   // this lane's entry of the list
  float thrD = INFINITY;                       // K-th best (broadcast)

  // prologue: stage tile 0 into buffer 0
#pragma unroll
  for (int s = 0; s < KNN_TILE/512; ++s)
    tile[s*512 + tid] = cpk[s*512 + tid];
  __syncthreads();

  int cur = 0;
  for (int t0 = 0; t0 < NC_PAD; t0 += KNN_TILE) {
    const int t1 = t0 + KNN_TILE;
    if (t1 < NC_PAD) {                         // stage next tile into other buf
#pragma unroll
      for (int s = 0; s < KNN_TILE/512; ++s)
        tile[(cur^1)*KNN_TILE + s*512 + tid] = cpk[t1 + s*512 + tid];
    }
    const float4* tb = tile + cur*KNN_TILE;
#pragma unroll
    for (int it = 0; it < KNN_TILE/256; ++it) {
      const int b = it*256;
      const float4 c0 = tb[b +   0 + lane];
      const float4 c1 = tb[b +  64 + lane];
      const float4 c2 = tb[b + 128 + lane];
      const float4 c3 = tb[b + 192 + lane];
      float u0 = __fmul_rn(qx, c0.x); u0 = __fmaf_rn(qy, c0.y, u0);
      const float dot0 = __fmaf_rn(qz, c0.z, u0);
      const float d20  = __fadd_rn(__fmaf_rn(-2.0f, dot0, qq), c0.w);
      float u1 = __fmul_rn(qx, c1.x); u1 = __fmaf_rn(qy, c1.y, u1);
      const float dot1 = __fmaf_rn(qz, c1.z, u1);
      const float d21  = __fadd_rn(__fmaf_rn(-2.0f, dot1, qq), c1.w);
      float u2 = __fmul_rn(qx, c2.x); u2 = __fmaf_rn(qy, c2.y, u2);
      const float dot2 = __fmaf_rn(qz, c2.z, u2);
      const float d22  = __fadd_rn(__fmaf_rn(-2.0f, dot2, qq), c2.w);
      float u3 = __fmul_rn(qx, c3.x); u3 = __fmaf_rn(qy, c3.y, u3);
      const float dot3 = __fmaf_rn(qz, c3.z, u3);
      const float d23  = __fadd_rn(__fmaf_rn(-2.0f, dot3, qq), c3.w);
      const float dmin = fminf(fminf(d20, d21), fminf(d22, d23));
      if (__ballot(dmin < thrD)) {             // no lane qualifies -> no insert
        KNN_INS(d20, t0 + b +   0)
        KNN_INS(d21, t0 + b +  64)
        KNN_INS(d22, t0 + b + 128)
        KNN_INS(d23, t0 + b + 192)
      }
    }
    __syncthreads();                           // next tile staged, cur consumed
    cur ^= 1;
  }
  if (lane < K) out_src[q*K + lane] = eI + c_off;
}

// ---------------------------------------------------------------------------
// LayerNorm + s/d projection, single-wave version (used by init branch).
// ---------------------------------------------------------------------------
__device__ __forceinline__ void ln_sd(
    float v, int node, int lane, int l,
    const float* __restrict__ ln_g, const float* __restrict__ ln_b,
    const float* __restrict__ Ws, const float* __restrict__ Wd,
    float* __restrict__ sbuf, float* __restrict__ dbuf)
{
  const float m = wave_sum64_dpp(v) * (1.0f/64.0f);
  const float c = v - m;
  const float var = wave_sum64_dpp(c*c) * (1.0f/64.0f);
  const float hn = c * rsqrtf(var + EPS) * ln_g[l*HD + lane] + ln_b[l*HD + lane];
  const float* ws = Ws + (size_t)l*HD*HD;
  const float* wd = Wd + (size_t)l*HD*HD;
  float accs = 0.0f, accd = 0.0f;
#pragma unroll
  for (int j = 0; j < HD; ++j) {
    const float hj = __shfl(hn, j);
    accs += hj * ws[j*HD + lane];
    accd += hj * wd[j*HD + lane];
  }
  sbuf[node*HD + lane] = accs;
  dbuf[node*HD + lane] = accd;
}

// init work for one node (verbatim init arithmetic; one wave per node).
__device__ __forceinline__ void init_node(
    int node, int lane,
    const float* __restrict__ atom_x, const float* __restrict__ vox_x,
    const float* __restrict__ Wa, const float* __restrict__ ba,
    const float* __restrict__ Wv, const float* __restrict__ bv,
    const float* __restrict__ ln_g, const float* __restrict__ ln_b,
    const float* __restrict__ Ws, const float* __restrict__ Wd,
    float* __restrict__ x, float* __restrict__ snap0,
    float* __restrict__ sbuf, float* __restrict__ dbuf)
{
  const float* in; const float* W; const float* b;
  if (node < NA) { in = atom_x + node*FEAT;     W = Wa; b = ba; }
  else           { in = vox_x + (node-NA)*FEAT; W = Wv; b = bv; }
  float acc = b[lane];
#pragma unroll
  for (int j = 0; j < FEAT; ++j) acc += in[j] * W[j*HD + lane];
  x[node*HD + lane] = acc;
  if (node >= NA) snap0[(node-NA)*HD + lane] = acc;
  ln_sd(acc, node, lane, 0, ln_g, ln_b, Ws, Wd, sbuf, dbuf);
}

// Merged dispatcher: 3 kNN scans + init (independent work) co-resident.
__global__ __launch_bounds__(512) void knn_all_kernel(
    const float* __restrict__ apos, const float* __restrict__ vpos,
    const float4* __restrict__ apk, const float4* __restrict__ vpk,
    int* __restrict__ srcA, int* __restrict__ srcAV, int* __restrict__ srcVV,
    const float* __restrict__ atom_x, const float* __restrict__ vox_x,
    const float* __restrict__ Wa, const float* __restrict__ ba,
    const float* __restrict__ Wv, const float* __restrict__ bv,
    const float* __restrict__ ln_g, const float* __restrict__ ln_b,
    const float* __restrict__ Ws, const float* __restrict__ Wd,
    float* __restrict__ x, float* __restrict__ snap0,
    float* __restrict__ sbuf0, float* __restrict__ dbuf)
{
  const int b = blockIdx.x;                   // block-uniform branch
  const int wid = threadIdx.x >> 6, lane = threadIdx.x & 63;
  if (b < NA/8)
    knn_body<10, NA_PAD>(apos, apk, 0,  srcA,  b);
  else if (b < 2*(NA/8))
    knn_body<15, NV_PAD>(apos, vpk, NA, srcAV, b - NA/8);
  else if (b < KNN_BLOCKS)
    knn_body<15, NV_PAD>(vpos, vpk, NA, srcVV, b - 2*(NA/8));
  else {
    const int node = (b - KNN_BLOCKS)*8 + wid;   // 1500 blocks x 8 = NN
    init_node(node, lane, atom_x, vox_x, Wa, ba, Wv, bv,
              ln_g, ln_b, Ws, Wd, x, snap0, sbuf0, dbuf);
  }
}

// ---------------------------------------------------------------------------
// Edge attribute MLP.
// ---------------------------------------------------------------------------
__device__ __forceinline__ void load_pos(const float* ap, const float* vp,
                                         int i, float& px, float& py, float& pz)
{
  const float* p = (i < NA) ? (ap + i*3) : (vp + (i - NA)*3);
  px = p[0]; py = p[1]; pz = p[2];
}

__global__ __launch_bounds__(256) void edge_attr_kernel(
    const float* __restrict__ atom_pos, const float* __restrict__ vox_pos,
    const int* __restrict__ srcA, const int* __restrict__ srcAV,
    const int* __restrict__ srcVV,
    const float* __restrict__ w1, const float* __restrict__ b1,
    const float* __restrict__ w2, const float* __restrict__ b2,
    float* __restrict__ eattr)
{
  const int e = blockIdx.x * 256 + threadIdx.x;
  if (e >= E_TOT) return;
  int s, d, mi;
  if (e < E_AA)              { mi = 0; s = srcA[e];                 d = e / 10; }
  else if (e < E_AA + E_AV)  { mi = 1; const int t = e - E_AA;      s = srcAV[t]; d = t / 15; }
  else                       { mi = 2; const int t = e - E_AA - E_AV; s = srcVV[t]; d = NA + t / 15; }
  float sx, sy, sz, dx_, dy_, dz_;
  load_pos(atom_pos, vox_pos, s, sx, sy, sz);
  load_pos(atom_pos, vox_pos, d, dx_, dy_, dz_);
  const float ex = sx - dx_, ey = sy - dy_, ez = sz - dz_;
  const float dist = sqrtf(ex*ex + ey*ey + ez*ez);
  float acc = b2[mi];
#pragma unroll
  for (int j = 0; j < 8; ++j) {
    float h = dist * w1[mi*8 + j] + b1[mi*8 + j];
    h = (h > 0.0f) ? h : 0.0f;
    acc += h * w2[mi*8 + j];
  }
  eattr[e] = acc;
}

// ---------------------------------------------------------------------------
// Per-node attention aggregation (r16/17, passing).
// ---------------------------------------------------------------------------
template<int NE, bool IS_ATOM>
__device__ __forceinline__ float agg_node(
    int n, int lane,
    float* __restrict__ x,
    const float* __restrict__ sbuf, const float* __restrict__ dbuf,
    const float* __restrict__ eattr,
    const int* __restrict__ srcA, const int* __restrict__ srcAV,
    const int* __restrict__ srcVV,
    const float* __restrict__ We, const float* __restrict__ att, int l,
    float* __restrict__ snap)
{
  const float wet  = We[l*HD + lane];
  const float attv = att[l*HD + lane];
  const float dn   = dbuf[n*HD + lane];

  int esrc[NE]; float eat[NE];
#pragma unroll
  for (int e = 0; e < NE; ++e) {
    int src, eidx;
    if (IS_ATOM) {
      if (e < 10) { src = srcA[n*10 + e];       eidx = n*10 + e; }
      else        { src = srcAV[n*15 + (e-10)]; eidx = E_AA + n*15 + (e-10); }
    } else {
      const int nv = n - NA;
      src = srcVV[nv*15 + e]; eidx = E_AA + E_AV + nv*15 + e;
    }
    esrc[e] = src;
    eat[e]  = eattr[eidx];
  }

  float srow[NE];
#pragma unroll
  for (int e = 0; e < NE; ++e) srow[e] = sbuf[esrc[e]*HD + lane];

  float escore[NE];
#pragma unroll
  for (int e = 0; e < NE; ++e) {
    float mm = srow[e] + dn + eat[e] * wet;
    mm = (mm >= 0.0f) ? mm : 0.2f * mm;        // leaky_relu(0.2)
    escore[e] = head_sum16_dpp(mm * attv);      // reduce over d within head
  }
  float mx = -INFINITY;
#pragma unroll
  for (int e = 0; e < NE; ++e) mx = fmaxf(mx, escore[e]);
  float den = 0.0f;
#pragma unroll
  for (int e = 0; e < NE; ++e) {
    const float a = __expf(escore[e] - mx);
    escore[e] = a; den += a;
  }
  const float inv = 1.0f / den;
  float msg = 0.0f;
#pragma unroll
  for (int e = 0; e < NE; ++e) msg += (escore[e] * inv) * srow[e];
  float xv = x[n*HD + lane] + msg;
  xv = (xv > 0.0f) ? xv : 0.0f;
  x[n*HD + lane] = xv;
  if (!IS_ATOM && snap != nullptr) snap[(n - NA)*HD + lane] = xv;
  return xv;
}

// ---------------------------------------------------------------------------
// Fused layer (r17/18/21 verbatim): 4 nodes/block agg, LN(l+1) + j-sliced
// s/d projection; hn exchange transposed ([HD][4]).
// ---------------------------------------------------------------------------
__global__ __launch_bounds__(256, 4) void layer_kernel(
    float* __restrict__ x,
    const float* __restrict__ sbuf_in, float* __restrict__ dbuf,
    float* __restrict__ sbuf_out,
    const float* __restrict__ eattr,
    const int* __restrict__ srcA, const int* __restrict__ srcAV,
    const int* __restrict__ srcVV,
    const float* __restrict__ We, const float* __restrict__ att,
    const float* __restrict__ ln_g, const float* __restrict__ ln_b,
    const float* __restrict__ Ws, const float* __restrict__ Wd,
    int l, float* __restrict__ snap, int do_next)
{
  const int wid = threadIdx.x >> 6, lane = threadIdx.x & 63;
  const int n = blockIdx.x * 4 + wid;       // blocks are node-type homogeneous
  __shared__ float hn_sh[HD][4];            // transposed: [j][node]
  __shared__ float part[4][4][2][HD];

  float xv;
  if (n < NA) {
    if (!do_next) return;                    // whole block returns uniformly
    xv = agg_node<25,true>(n, lane, x, sbuf_in, dbuf, eattr,
                           srcA, srcAV, srcVV, We, att, l, nullptr);
  } else {
    xv = agg_node<15,false>(n, lane, x, sbuf_in, dbuf, eattr,
                            srcA, srcAV, srcVV, We, att, l, snap);
  }
  if (!do_next) return;

  // LayerNorm for layer l+1 (DPP wave sums)
  const int ln = l + 1;
  const float mean = wave_sum64_dpp(xv) * (1.0f/64.0f);
  const float cc   = xv - mean;
  const float var  = wave_sum64_dpp(cc*cc) * (1.0f/64.0f);
  const float hn   = cc * rsqrtf(var + EPS) * ln_g[ln*HD + lane] + ln_b[ln*HD + lane];
  hn_sh[lane][wid] = hn;
  __syncthreads();

  // j-sliced projection: wave wid covers j in [wid*16, wid*16+16) for 4 nodes
  const float* wsp = Ws + (size_t)ln*HD*HD;
  const float* wdp = Wd + (size_t)ln*HD*HD;
  float as0=0.f, as1=0.f, as2=0.f, as3=0.f;
  float ad0=0.f, ad1=0.f, ad2=0.f, ad3=0.f;
#pragma unroll
  for (int jj = 0; jj < 16; ++jj) {
    const int j = wid*16 + jj;
    const float wvs = wsp[j*HD + lane];
    const float wvd = wdp[j*HD + lane];
    const float4 h = *(const float4*)&hn_sh[j][0];   // one ds_read_b128
    as0 += h.x*wvs; ad0 += h.x*wvd;
    as1 += h.y*wvs; ad1 += h.y*wvd;
    as2 += h.z*wvs; ad2 += h.z*wvd;
    as3 += h.w*wvs; ad3 += h.w*wvd;
  }
  part[wid][0][0][lane] = as0; part[wid][0][1][lane] = ad0;
  part[wid][1][0][lane] = as1; part[wid][1][1][lane] = ad1;
  part[wid][2][0][lane] = as2; part[wid][2][1][lane] = ad2;
  part[wid][3][0][lane] = as3; part[wid][3][1][lane] = ad3;
  __syncthreads();

  const float accs = ((part[0][wid][0][lane] + part[1][wid][0][lane])
                    + (part[2][wid][0][lane] + part[3][wid][0][lane]));
  const float accd = ((part[0][wid][1][lane] + part[1][wid][1][lane])
                    + (part[2][wid][1][lane] + part[3][wid][1][lane]));
  sbuf_out[n*HD + lane] = accs;
  dbuf[n*HD + lane]     = accd;
}

// ---------------------------------------------------------------------------
// Output head: 4 vox nodes/block, j-sliced matmuls amortize weight loads 4x.
// ---------------------------------------------------------------------------
__global__ __launch_bounds__(256) void head_kernel(
    const float* __restrict__ snaps,
    const float* __restrict__ Wo1, const float* __restrict__ bo1,
    const float* __restrict__ Wo2, const float* __restrict__ bo2,
    float* __restrict__ out)
{
  const int wid = threadIdx.x >> 6, lane = threadIdx.x & 63;
  const int n = blockIdx.x * 4 + wid;
  __shared__ float cat[4][7*HD];
  __shared__ float part[4][4][HD];
  __shared__ float o1[4][HD];

#pragma unroll
  for (int c = 0; c < 7; ++c)
    cat[wid][c*HD + lane] = snaps[(size_t)c*NV*HD + n*HD + lane];
  __syncthreads();

  float a0=0.f, a1=0.f, a2=0.f, a3=0.f;
  for (int jj = 0; jj < 112; ++jj) {
    const int j = wid*112 + jj;
    const float w = Wo1[j*HD + lane];
    a0 += cat[0][j]*w; a1 += cat[1][j]*w;
    a2 += cat[2][j]*w; a3 += cat[3][j]*w;
  }
  part[wid][0][lane] = a0; part[wid][1][lane] = a1;
  part[wid][2][lane] = a2; part[wid][3][lane] = a3;
  __syncthreads();

  float acc = bo1[lane] + ((part[0][wid][lane] + part[1][wid][lane])
                         + (part[2][wid][lane] + part[3][wid][lane]));
  acc = fmaxf(acc, 0.0f);
  o1[wid][lane] = acc;
  __syncthreads();

  float b0=0.f, b1=0.f, b2=0.f, b3=0.f;
#pragma unroll
  for (int jj = 0; jj < 16; ++jj) {
    const int j = wid*16 + jj;
    const float w = Wo2[j*HD + lane];
    b0 += o1[0][j]*w; b1 += o1[1][j]*w;
    b2 += o1[2][j]*w; b3 += o1[3][j]*w;
  }
  __syncthreads();                       // part reuse
  part[wid][0][lane] = b0; part[wid][1][lane] = b1;
  part[wid][2][lane] = b2; part[wid][3][lane] = b3;
  __syncthreads();

  const float acc2 = bo2[lane] + ((part[0][wid][lane] + part[1][wid][lane])
                                + (part[2][wid][lane] + part[3][wid][lane]));
  out[n*HD + lane] = acc2;
}

__global__ __launch_bounds__(256) void copy_pos_kernel(
    const float* __restrict__ vp, float* __restrict__ out)
{
  const int i = blockIdx.x * 256 + threadIdx.x;
  if (i < NV*3) out[ENC_SIZE + i] = vp[i];
}

// ---------------------------------------------------------------------------
extern "C" void kernel_launch(void* const* d_in, const int* in_sizes, int n_in,
                              void* d_out, int out_size, void* d_ws, size_t ws_size,
                              hipStream_t stream)
{
  const float* atom_x    = (const float*)d_in[0];
  const float* atom_pos  = (const float*)d_in[1];
  const float* vox_x     = (const float*)d_in[2];
  const float* vox_pos   = (const float*)d_in[3];
  const float* W_atom_in = (const float*)d_in[4];
  const float* b_atom_in = (const float*)d_in[5];
  const float* W_vox_in  = (const float*)d_in[6];
  const float* b_vox_in  = (const float*)d_in[7];
  const float* emlp_w1   = (const float*)d_in[8];
  const float* emlp_b1   = (const float*)d_in[9];
  const float* emlp_w2   = (const float*)d_in[10];
  const float* emlp_b2   = (const float*)d_in[11];
  const float* ln_g      = (const float*)d_in[12];
  const float* ln_b      = (const float*)d_in[13];
  const float* Ws        = (const float*)d_in[14];
  const float* Wd        = (const float*)d_in[15];
  const float* We        = (const float*)d_in[16];
  const float* att       = (const float*)d_in[17];
  const float* Wo1       = (const float*)d_in[18];
  const float* bo1       = (const float*)d_in[19];
  const float* Wo2       = (const float*)d_in[20];
  const float* bo2       = (const float*)d_in[21];
  float* out = (float*)d_out;

  // workspace layout (floats), ~21.8 MB
  float* ws    = (float*)d_ws;
  float* x     = ws;                          // [NN][HD]
  float* sA    = x  + (size_t)NN*HD;          // [NN][HD] sbuf ping
  float* sB    = sA + (size_t)NN*HD;          // [NN][HD] sbuf pong
  float* dbuf  = sB + (size_t)NN*HD;          // [NN][HD]
  float* eattr = dbuf + (size_t)NN*HD;        // [E_TOT]
  float* snaps = eattr + E_TOT;               // [7][NV][HD]
  int*   srcA  = (int*)(snaps + (size_t)7*NV*HD);
  int*   srcAV = srcA  + E_AA;
  int*   srcVV = srcAV + E_AV;
  float4* apk  = (float4*)(srcVV + E_VV);     // [NA_PAD] packed atoms
  float4* vpk  = apk + NA_PAD;                // [NV_PAD] packed voxels

  // 1. pack candidates, then merged kNN (dbuf-staged) + init co-resident
  pack_kernel<<<(NA_PAD + NV_PAD + 255)/256, 256, 0, stream>>>(
      atom_pos, vox_pos, apk, vpk);
  knn_all_kernel<<<KNN_BLOCKS + INIT_BLOCKS, 512, 2*KNN_TILE*sizeof(float4), stream>>>(
      atom_pos, vox_pos, apk, vpk, srcA, srcAV, srcVV,
      atom_x, vox_x, W_atom_in, b_atom_in, W_vox_in, b_vox_in,
      ln_g, ln_b, Ws, Wd, x, snaps, sA, dbuf);
  // 2. edge attributes
  edge_attr_kernel<<<(E_TOT + 255)/256, 256, 0, stream>>>(
      atom_pos, vox_pos, srcA, srcAV, srcVV,
      emlp_w1, emlp_b1, emlp_w2, emlp_b2, eattr);
  // 3. 12 fused GAT layers (per-layer dispatch keeps L2 warm across layers)
  for (int l = 0; l < NLAYER; ++l) {
    float* s_in  = (l & 1) ? sB : sA;
    float* s_out = (l & 1) ? sA : sB;
    float* snap  = (l & 1) ? (snaps + (size_t)(l/2 + 1)*NV*HD) : nullptr;
    layer_kernel<<<NGRP, 256, 0, stream>>>(x, s_in, dbuf, s_out, eattr,
                                           srcA, srcAV, srcVV, We, att,
                                           ln_g, ln_b, Ws, Wd, l, snap,
                                           (l < NLAYER-1) ? 1 : 0);
  }
  // 4. output head + vox_pos passthrough
  head_kernel<<<NV/4, 256, 0, stream>>>(snaps, Wo1, bo1, Wo2, bo2, out);
  copy_pos_kernel<<<(NV*3 + 255)/256, 256, 0, stream>>>(vox_pos, out);
}

// Round 29
// 325.531 us; speedup vs baseline: 1.6769x; 1.0269x over previous
//
#include <hip/hip_runtime.h>
#include <math.h>

#define NA 8000
#define NV 4000
#define NN 12000
#define NA_PAD 8192
#define NV_PAD 4096
#define KNN_TILE 1024
#define FEAT 32
#define HD 64
#define NLAYER 12
#define E_AA 80000
#define E_AV 120000
#define E_VV 60000
#define E_TOT 260000
#define ENC_SIZE (NV * HD)
#define EPS 1e-5f
#define NGRP (NN/4)
#define KNN_BLOCKS (NA/8 + NA/8 + NV/8)   // 2500
#define INIT_BLOCKS (NN/8)                 // 1500

__device__ __forceinline__ float wave_sum64(float v) {
#pragma unroll
  for (int off = 1; off < 64; off <<= 1) v += __shfl_xor(v, off);
  return v;
}

// DPP butterfly helpers: pure VALU (v_add_f32_dpp), no DS pipe.
__device__ __forceinline__ float dpp_step(float v, const int ctrl) {
  int p;
  switch (ctrl) {
    case 0xB1:  p = __builtin_amdgcn_update_dpp(0, __float_as_int(v), 0xB1,  0xF, 0xF, true); break;
    case 0x4E:  p = __builtin_amdgcn_update_dpp(0, __float_as_int(v), 0x4E,  0xF, 0xF, true); break;
    case 0x141: p = __builtin_amdgcn_update_dpp(0, __float_as_int(v), 0x141, 0xF, 0xF, true); break;
    default:    p = __builtin_amdgcn_update_dpp(0, __float_as_int(v), 0x140, 0xF, 0xF, true); break;
  }
  return v + __int_as_float(p);
}

__device__ __forceinline__ float head_sum16_dpp(float v) {
  v = dpp_step(v, 0xB1);
  v = dpp_step(v, 0x4E);
  v = dpp_step(v, 0x141);
  v = dpp_step(v, 0x140);
  return v;
}

__device__ __forceinline__ float wave_sum64_dpp(float v) {
  v = head_sum16_dpp(v);
  v += __shfl_xor(v, 16);
  v += __shfl_xor(v, 32);
  return v;
}

// DPP wave_shr:1 (ctrl 0x138): pure-VALU __shfl_up(x,1); lane-0 shifted
// values are dead in the insert (pS forced to 1). (r27, passing)
__device__ __forceinline__ float dpp_shr1_f(float v) {
  const int p = __builtin_amdgcn_update_dpp(0, __float_as_int(v), 0x138, 0xF, 0xF, true);
  return __int_as_float(p);
}
__device__ __forceinline__ int dpp_shr1_i(int v) {
  return __builtin_amdgcn_update_dpp(0, v, 0x138, 0xF, 0xF, true);
}

// ---------------------------------------------------------------------------
// Pack candidate positions as [x, y, z, |c|^2] float4, padded with cc=+INF.
// (FROZEN)
// ---------------------------------------------------------------------------
__global__ __launch_bounds__(256) void pack_kernel(
    const float* __restrict__ apos, const float* __restrict__ vpos,
    float4* __restrict__ apk, float4* __restrict__ vpk)
{
  const int i = blockIdx.x * 256 + threadIdx.x;
  if (i < NA_PAD) {
    float4 r;
    if (i < NA) {
      const float cx = apos[i*3+0], cy = apos[i*3+1], cz = apos[i*3+2];
      r = make_float4(cx, cy, cz, (cx*cx + cy*cy) + cz*cz);
    } else r = make_float4(0.f, 0.f, 0.f, INFINITY);
    apk[i] = r;
  } else {
    const int j = i - NA_PAD;
    if (j < NV_PAD) {
      float4 r;
      if (j < NV) {
        const float cx = vpos[j*3+0], cy = vpos[j*3+1], cz = vpos[j*3+2];
        r = make_float4(cx, cy, cz, (cx*cx + cy*cy) + cz*cz);
      } else r = make_float4(0.f, 0.f, 0.f, INFINITY);
      vpk[j] = r;
    }
  }
}

// ---------------------------------------------------------------------------
// Batched brute-force kNN (r26-r28, passing, FROZEN): pinned d2, DPP insert,
// double-buffered staging.
// ---------------------------------------------------------------------------
#define KNN_INS(D2, JB)                                                \
  {                                                                    \
    unsigned long long m = __ballot((D2) < thrD);                      \
    if (m) {                                                           \
      do {                                                             \
        const int sl = __ffsll(m) - 1;                                 \
        m &= (m - 1ULL);                                               \
        const float v  = __shfl((D2), sl);                             \
        const int   vi = (JB) + sl;                                    \
        const bool stay = (eD < v) || (eD == v && eI < vi);            \
        const float pD = dpp_shr1_f(eD);                               \
        const int   pI = dpp_shr1_i(eI);                               \
        int pS = dpp_shr1_i(stay ? 1 : 0);                             \
        if (lane == 0) pS = 1;                                         \
        eD = stay ? eD : (pS ? v  : pD);                               \
        eI = stay ? eI : (pS ? vi : pI);                               \
      } while (m);                                                     \
      thrD = __shfl(eD, K-1);                                          \
    }                                                                  \
  }

template<int K, int NC_PAD>
__device__ __attribute__((noinline)) void knn_body(
    const float* __restrict__ qpos, const float4* __restrict__ cpk,
    int c_off, int* __restrict__ out_src, int qblock)
{
  extern __shared__ float4 tile[];            // [2][KNN_TILE]
  const int tid  = threadIdx.x;
  const int wid  = tid >> 6, lane = tid & 63;
  const int q    = qblock * 8 + wid;
  const float qx = qpos[q*3+0], qy = qpos[q*3+1], qz = qpos[q*3+2];
  float qt = __fmul_rn(qx, qx);
  qt = __fmaf_rn(qy, qy, qt);
  const float qq = __fmaf_rn(qz, qz, qt);     // pinned (r23-verified seq)

  float eD = INFINITY; int eI = 0x7fffffff;   // this lane's entry of the list
  float thrD = INFINITY;                       // K-th best (broadcast)

  // prologue: stage tile 0 into buffer 0
#pragma unroll
  for (int s = 0; s < KNN_TILE/512; ++s)
    tile[s*512 + tid] = cpk[s*512 + tid];
  __syncthreads();

  int cur = 0;
  for (int t0 = 0; t0 < NC_PAD; t0 += KNN_TILE) {
    const int t1 = t0 + KNN_TILE;
    if (t1 < NC_PAD) {                         // stage next tile into other buf
#pragma unroll
      for (int s = 0; s < KNN_TILE/512; ++s)
        tile[(cur^1)*KNN_TILE + s*512 + tid] = cpk[t1 + s*512 + tid];
    }
    const float4* tb = tile + cur*KNN_TILE;
#pragma unroll
    for (int it = 0; it < KNN_TILE/256; ++it) {
      const int b = it*256;
      const float4 c0 = tb[b +   0 + lane];
      const float4 c1 = tb[b +  64 + lane];
      const float4 c2 = tb[b + 128 + lane];
      const float4 c3 = tb[b + 192 + lane];
      float u0 = __fmul_rn(qx, c0.x); u0 = __fmaf_rn(qy, c0.y, u0);
      const float dot0 = __fmaf_rn(qz, c0.z, u0);
      const float d20  = __fadd_rn(__fmaf_rn(-2.0f, dot0, qq), c0.w);
      float u1 = __fmul_rn(qx, c1.x); u1 = __fmaf_rn(qy, c1.y, u1);
      const float dot1 = __fmaf_rn(qz, c1.z, u1);
      const float d21  = __fadd_rn(__fmaf_rn(-2.0f, dot1, qq), c1.w);
      float u2 = __fmul_rn(qx, c2.x); u2 = __fmaf_rn(qy, c2.y, u2);
      const float dot2 = __fmaf_rn(qz, c2.z, u2);
      const float d22  = __fadd_rn(__fmaf_rn(-2.0f, dot2, qq), c2.w);
      float u3 = __fmul_rn(qx, c3.x); u3 = __fmaf_rn(qy, c3.y, u3);
      const float dot3 = __fmaf_rn(qz, c3.z, u3);
      const float d23  = __fadd_rn(__fmaf_rn(-2.0f, dot3, qq), c3.w);
      const float dmin = fminf(fminf(d20, d21), fminf(d22, d23));
      if (__ballot(dmin < thrD)) {             // no lane qualifies -> no insert
        KNN_INS(d20, t0 + b +   0)
        KNN_INS(d21, t0 + b +  64)
        KNN_INS(d22, t0 + b + 128)
        KNN_INS(d23, t0 + b + 192)
      }
    }
    __syncthreads();                           // next tile staged, cur consumed
    cur ^= 1;
  }
  if (lane < K) out_src[q*K + lane] = eI + c_off;
}

// ---------------------------------------------------------------------------
// LayerNorm + s/d projection, single-wave version (used by init branch).
// ---------------------------------------------------------------------------
__device__ __forceinline__ void ln_sd(
    float v, int node, int lane, int l,
    const float* __restrict__ ln_g, const float* __restrict__ ln_b,
    const float* __restrict__ Ws, const float* __restrict__ Wd,
    float* __restrict__ sbuf, float* __restrict__ dbuf)
{
  const float m = wave_sum64_dpp(v) * (1.0f/64.0f);
  const float c = v - m;
  const float var = wave_sum64_dpp(c*c) * (1.0f/64.0f);
  const float hn = c * rsqrtf(var + EPS) * ln_g[l*HD + lane] + ln_b[l*HD + lane];
  const float* ws = Ws + (size_t)l*HD*HD;
  const float* wd = Wd + (size_t)l*HD*HD;
  float accs = 0.0f, accd = 0.0f;
#pragma unroll
  for (int j = 0; j < HD; ++j) {
    const float hj = __shfl(hn, j);
    accs += hj * ws[j*HD + lane];
    accd += hj * wd[j*HD + lane];
  }
  sbuf[node*HD + lane] = accs;
  dbuf[node*HD + lane] = accd;
}

// init work for one node (verbatim init arithmetic; one wave per node).
__device__ __forceinline__ void init_node(
    int node, int lane,
    const float* __restrict__ atom_x, const float* __restrict__ vox_x,
    const float* __restrict__ Wa, const float* __restrict__ ba,
    const float* __restrict__ Wv, const float* __restrict__ bv,
    const float* __restrict__ ln_g, const float* __restrict__ ln_b,
    const float* __restrict__ Ws, const float* __restrict__ Wd,
    float* __restrict__ x, float* __restrict__ snap0,
    float* __restrict__ sbuf, float* __restrict__ dbuf)
{
  const float* in; const float* W; const float* b;
  if (node < NA) { in = atom_x + node*FEAT;     W = Wa; b = ba; }
  else           { in = vox_x + (node-NA)*FEAT; W = Wv; b = bv; }
  float acc = b[lane];
#pragma unroll
  for (int j = 0; j < FEAT; ++j) acc += in[j] * W[j*HD + lane];
  x[node*HD + lane] = acc;
  if (node >= NA) snap0[(node-NA)*HD + lane] = acc;
  ln_sd(acc, node, lane, 0, ln_g, ln_b, Ws, Wd, sbuf, dbuf);
}

// Merged dispatcher: 3 kNN scans + init (independent work) co-resident.
__global__ __launch_bounds__(512) void knn_all_kernel(
    const float* __restrict__ apos, const float* __restrict__ vpos,
    const float4* __restrict__ apk, const float4* __restrict__ vpk,
    int* __restrict__ srcA, int* __restrict__ srcAV, int* __restrict__ srcVV,
    const float* __restrict__ atom_x, const float* __restrict__ vox_x,
    const float* __restrict__ Wa, const float* __restrict__ ba,
    const float* __restrict__ Wv, const float* __restrict__ bv,
    const float* __restrict__ ln_g, const float* __restrict__ ln_b,
    const float* __restrict__ Ws, const float* __restrict__ Wd,
    float* __restrict__ x, float* __restrict__ snap0,
    float* __restrict__ sbuf0, float* __restrict__ dbuf)
{
  const int b = blockIdx.x;                   // block-uniform branch
  const int wid = threadIdx.x >> 6, lane = threadIdx.x & 63;
  if (b < NA/8)
    knn_body<10, NA_PAD>(apos, apk, 0,  srcA,  b);
  else if (b < 2*(NA/8))
    knn_body<15, NV_PAD>(apos, vpk, NA, srcAV, b - NA/8);
  else if (b < KNN_BLOCKS)
    knn_body<15, NV_PAD>(vpos, vpk, NA, srcVV, b - 2*(NA/8));
  else {
    const int node = (b - KNN_BLOCKS)*8 + wid;   // 1500 blocks x 8 = NN
    init_node(node, lane, atom_x, vox_x, Wa, ba, Wv, bv,
              ln_g, ln_b, Ws, Wd, x, snap0, sbuf0, dbuf);
  }
}

// ---------------------------------------------------------------------------
// Edge attribute MLP.
// ---------------------------------------------------------------------------
__device__ __forceinline__ void load_pos(const float* ap, const float* vp,
                                         int i, float& px, float& py, float& pz)
{
  const float* p = (i < NA) ? (ap + i*3) : (vp + (i - NA)*3);
  px = p[0]; py = p[1]; pz = p[2];
}

__global__ __launch_bounds__(256) void edge_attr_kernel(
    const float* __restrict__ atom_pos, const float* __restrict__ vox_pos,
    const int* __restrict__ srcA, const int* __restrict__ srcAV,
    const int* __restrict__ srcVV,
    const float* __restrict__ w1, const float* __restrict__ b1,
    const float* __restrict__ w2, const float* __restrict__ b2,
    float* __restrict__ eattr)
{
  const int e = blockIdx.x * 256 + threadIdx.x;
  if (e >= E_TOT) return;
  int s, d, mi;
  if (e < E_AA)              { mi = 0; s = srcA[e];                 d = e / 10; }
  else if (e < E_AA + E_AV)  { mi = 1; const int t = e - E_AA;      s = srcAV[t]; d = t / 15; }
  else                       { mi = 2; const int t = e - E_AA - E_AV; s = srcVV[t]; d = NA + t / 15; }
  float sx, sy, sz, dx_, dy_, dz_;
  load_pos(atom_pos, vox_pos, s, sx, sy, sz);
  load_pos(atom_pos, vox_pos, d, dx_, dy_, dz_);
  const float ex = sx - dx_, ey = sy - dy_, ez = sz - dz_;
  const float dist = sqrtf(ex*ex + ey*ey + ez*ez);
  float acc = b2[mi];
#pragma unroll
  for (int j = 0; j < 8; ++j) {
    float h = dist * w1[mi*8 + j] + b1[mi*8 + j];
    h = (h > 0.0f) ? h : 0.0f;
    acc += h * w2[mi*8 + j];
  }
  eattr[e] = acc;
}

// ---------------------------------------------------------------------------
// Chunked aggregation: one chunk of NE edges starting at E0. Computes the
// chunk's (max, sum exp, sum exp*srow) with chunk-sized register arrays
// (halves live VGPR vs the monolithic version -> higher occupancy).
// ---------------------------------------------------------------------------
template<int NE, int E0, bool IS_ATOM>
__device__ __forceinline__ void agg_chunk(
    int n, int lane,
    const float* __restrict__ sbuf, const float* __restrict__ eattr,
    const int* __restrict__ srcA, const int* __restrict__ srcAV,
    const int* __restrict__ srcVV,
    float dn, float wet, float attv,
    float& mC, float& denC, float& msgC)
{
  int esrc[NE]; float eat[NE];
#pragma unroll
  for (int i = 0; i < NE; ++i) {
    const int e = E0 + i;
    int src, eidx;
    if (IS_ATOM) {
      if (e < 10) { src = srcA[n*10 + e];       eidx = n*10 + e; }
      else        { src = srcAV[n*15 + (e-10)]; eidx = E_AA + n*15 + (e-10); }
    } else {
      const int nv = n - NA;
      src = srcVV[nv*15 + e]; eidx = E_AA + E_AV + nv*15 + e;
    }
    esrc[i] = src;
    eat[i]  = eattr[eidx];
  }
  float srow[NE];
#pragma unroll
  for (int i = 0; i < NE; ++i) srow[i] = sbuf[esrc[i]*HD + lane];
  float escore[NE];
#pragma unroll
  for (int i = 0; i < NE; ++i) {
    float mm = srow[i] + dn + eat[i] * wet;
    mm = (mm >= 0.0f) ? mm : 0.2f * mm;        // leaky_relu(0.2)
    escore[i] = head_sum16_dpp(mm * attv);      // reduce over d within head
  }
  mC = -INFINITY;
#pragma unroll
  for (int i = 0; i < NE; ++i) mC = fmaxf(mC, escore[i]);
  denC = 0.0f; msgC = 0.0f;
#pragma unroll
  for (int i = 0; i < NE; ++i) {
    const float a = __expf(escore[i] - mC);
    denC += a;
    msgC = __fmaf_rn(a, srow[i], msgC);
  }
}

// Per-node aggregation via 2-chunk ONLINE SOFTMAX (continuous reassociation
// only — same class as the passing r5 j-slice / r11 half-sum; no discrete
// decisions downstream). Atoms: 13+12; vox: 8+7.
template<bool IS_ATOM>
__device__ __forceinline__ float agg_node(
    int n, int lane,
    float* __restrict__ x,
    const float* __restrict__ sbuf, const float* __restrict__ dbuf,
    const float* __restrict__ eattr,
    const int* __restrict__ srcA, const int* __restrict__ srcAV,
    const int* __restrict__ srcVV,
    const float* __restrict__ We, const float* __restrict__ att, int l,
    float* __restrict__ snap)
{
  const float wet  = We[l*HD + lane];
  const float attv = att[l*HD + lane];
  const float dn   = dbuf[n*HD + lane];

  float m1, d1, g1, m2, d2, g2;
  if (IS_ATOM) {
    agg_chunk<13, 0, true>(n, lane, sbuf, eattr, srcA, srcAV, srcVV,
                           dn, wet, attv, m1, d1, g1);
    agg_chunk<12, 13, true>(n, lane, sbuf, eattr, srcA, srcAV, srcVV,
                            dn, wet, attv, m2, d2, g2);
  } else {
    agg_chunk<8, 0, false>(n, lane, sbuf, eattr, srcA, srcAV, srcVV,
                           dn, wet, attv, m1, d1, g1);
    agg_chunk<7, 8, false>(n, lane, sbuf, eattr, srcA, srcAV, srcVV,
                           dn, wet, attv, m2, d2, g2);
  }
  const float m  = fmaxf(m1, m2);
  const float s1 = __expf(m1 - m);
  const float s2 = __expf(m2 - m);
  const float den = __fmaf_rn(d1, s1, d2 * s2);
  const float msg = __fmaf_rn(g1, s1, g2 * s2) / den;

  float xv = x[n*HD + lane] + msg;
  xv = (xv > 0.0f) ? xv : 0.0f;
  x[n*HD + lane] = xv;
  if (!IS_ATOM && snap != nullptr) snap[(n - NA)*HD + lane] = xv;
  return xv;
}

// ---------------------------------------------------------------------------
// Fused layer: 4 nodes/block agg (2-chunk online softmax), LN(l+1) +
// j-sliced s/d projection; hn exchange transposed ([HD][4]).
// ---------------------------------------------------------------------------
__global__ __launch_bounds__(256, 4) void layer_kernel(
    float* __restrict__ x,
    const float* __restrict__ sbuf_in, float* __restrict__ dbuf,
    float* __restrict__ sbuf_out,
    const float* __restrict__ eattr,
    const int* __restrict__ srcA, const int* __restrict__ srcAV,
    const int* __restrict__ srcVV,
    const float* __restrict__ We, const float* __restrict__ att,
    const float* __restrict__ ln_g, const float* __restrict__ ln_b,
    const float* __restrict__ Ws, const float* __restrict__ Wd,
    int l, float* __restrict__ snap, int do_next)
{
  const int wid = threadIdx.x >> 6, lane = threadIdx.x & 63;
  const int n = blockIdx.x * 4 + wid;       // blocks are node-type homogeneous
  __shared__ float hn_sh[HD][4];            // transposed: [j][node]
  __shared__ float part[4][4][2][HD];

  float xv;
  if (n < NA) {
    if (!do_next) return;                    // whole block returns uniformly
    xv = agg_node<true>(n, lane, x, sbuf_in, dbuf, eattr,
                        srcA, srcAV, srcVV, We, att, l, nullptr);
  } else {
    xv = agg_node<false>(n, lane, x, sbuf_in, dbuf, eattr,
                         srcA, srcAV, srcVV, We, att, l, snap);
  }
  if (!do_next) return;

  // LayerNorm for layer l+1 (DPP wave sums)
  const int ln = l + 1;
  const float mean = wave_sum64_dpp(xv) * (1.0f/64.0f);
  const float cc   = xv - mean;
  const float var  = wave_sum64_dpp(cc*cc) * (1.0f/64.0f);
  const float hn   = cc * rsqrtf(var + EPS) * ln_g[ln*HD + lane] + ln_b[ln*HD + lane];
  hn_sh[lane][wid] = hn;
  __syncthreads();

  // j-sliced projection: wave wid covers j in [wid*16, wid*16+16) for 4 nodes
  const float* wsp = Ws + (size_t)ln*HD*HD;
  const float* wdp = Wd + (size_t)ln*HD*HD;
  float as0=0.f, as1=0.f, as2=0.f, as3=0.f;
  float ad0=0.f, ad1=0.f, ad2=0.f, ad3=0.f;
#pragma unroll
  for (int jj = 0; jj < 16; ++jj) {
    const int j = wid*16 + jj;
    const float wvs = wsp[j*HD + lane];
    const float wvd = wdp[j*HD + lane];
    const float4 h = *(const float4*)&hn_sh[j][0];   // one ds_read_b128
    as0 += h.x*wvs; ad0 += h.x*wvd;
    as1 += h.y*wvs; ad1 += h.y*wvd;
    as2 += h.z*wvs; ad2 += h.z*wvd;
    as3 += h.w*wvs; ad3 += h.w*wvd;
  }
  part[wid][0][0][lane] = as0; part[wid][0][1][lane] = ad0;
  part[wid][1][0][lane] = as1; part[wid][1][1][lane] = ad1;
  part[wid][2][0][lane] = as2; part[wid][2][1][lane] = ad2;
  part[wid][3][0][lane] = as3; part[wid][3][1][lane] = ad3;
  __syncthreads();

  const float accs = ((part[0][wid][0][lane] + part[1][wid][0][lane])
                    + (part[2][wid][0][lane] + part[3][wid][0][lane]));
  const float accd = ((part[0][wid][1][lane] + part[1][wid][1][lane])
                    + (part[2][wid][1][lane] + part[3][wid][1][lane]));
  sbuf_out[n*HD + lane] = accs;
  dbuf[n*HD + lane]     = accd;
}

// ---------------------------------------------------------------------------
// Output head: 4 vox nodes/block, j-sliced matmuls amortize weight loads 4x.
// ---------------------------------------------------------------------------
__global__ __launch_bounds__(256) void head_kernel(
    const float* __restrict__ snaps,
    const float* __restrict__ Wo1, const float* __restrict__ bo1,
    const float* __restrict__ Wo2, const float* __restrict__ bo2,
    float* __restrict__ out)
{
  const int wid = threadIdx.x >> 6, lane = threadIdx.x & 63;
  const int n = blockIdx.x * 4 + wid;
  __shared__ float cat[4][7*HD];
  __shared__ float part[4][4][HD];
  __shared__ float o1[4][HD];

#pragma unroll
  for (int c = 0; c < 7; ++c)
    cat[wid][c*HD + lane] = snaps[(size_t)c*NV*HD + n*HD + lane];
  __syncthreads();

  float a0=0.f, a1=0.f, a2=0.f, a3=0.f;
  for (int jj = 0; jj < 112; ++jj) {
    const int j = wid*112 + jj;
    const float w = Wo1[j*HD + lane];
    a0 += cat[0][j]*w; a1 += cat[1][j]*w;
    a2 += cat[2][j]*w; a3 += cat[3][j]*w;
  }
  part[wid][0][lane] = a0; part[wid][1][lane] = a1;
  part[wid][2][lane] = a2; part[wid][3][lane] = a3;
  __syncthreads();

  float acc = bo1[lane] + ((part[0][wid][lane] + part[1][wid][lane])
                         + (part[2][wid][lane] + part[3][wid][lane]));
  acc = fmaxf(acc, 0.0f);
  o1[wid][lane] = acc;
  __syncthreads();

  float b0=0.f, b1=0.f, b2=0.f, b3=0.f;
#pragma unroll
  for (int jj = 0; jj < 16; ++jj) {
    const int j = wid*16 + jj;
    const float w = Wo2[j*HD + lane];
    b0 += o1[0][j]*w; b1 += o1[1][j]*w;
    b2 += o1[2][j]*w; b3 += o1[3][j]*w;
  }
  __syncthreads();                       // part reuse
  part[wid][0][lane] = b0; part[wid][1][lane] = b1;
  part[wid][2][lane] = b2; part[wid][3][lane] = b3;
  __syncthreads();

  const float acc2 = bo2[lane] + ((part[0][wid][lane] + part[1][wid][lane])
                                + (part[2][wid][lane] + part[3][wid][lane]));
  out[n*HD + lane] = acc2;
}

__global__ __launch_bounds__(256) void copy_pos_kernel(
    const float* __restrict__ vp, float* __restrict__ out)
{
  const int i = blockIdx.x * 256 + threadIdx.x;
  if (i < NV*3) out[ENC_SIZE + i] = vp[i];
}

// ---------------------------------------------------------------------------
extern "C" void kernel_launch(void* const* d_in, const int* in_sizes, int n_in,
                              void* d_out, int out_size, void* d_ws, size_t ws_size,
                              hipStream_t stream)
{
  const float* atom_x    = (const float*)d_in[0];
  const float* atom_pos  = (const float*)d_in[1];
  const float* vox_x     = (const float*)d_in[2];
  const float* vox_pos   = (const float*)d_in[3];
  const float* W_atom_in = (const float*)d_in[4];
  const float* b_atom_in = (const float*)d_in[5];
  const float* W_vox_in  = (const float*)d_in[6];
  const float* b_vox_in  = (const float*)d_in[7];
  const float* emlp_w1   = (const float*)d_in[8];
  const float* emlp_b1   = (const float*)d_in[9];
  const float* emlp_w2   = (const float*)d_in[10];
  const float* emlp_b2   = (const float*)d_in[11];
  const float* ln_g      = (const float*)d_in[12];
  const float* ln_b      = (const float*)d_in[13];
  const float* Ws        = (const float*)d_in[14];
  const float* Wd        = (const float*)d_in[15];
  const float* We        = (const float*)d_in[16];
  const float* att       = (const float*)d_in[17];
  const float* Wo1       = (const float*)d_in[18];
  const float* bo1       = (const float*)d_in[19];
  const float* Wo2       = (const float*)d_in[20];
  const float* bo2       = (const float*)d_in[21];
  float* out = (float*)d_out;

  // workspace layout (floats), ~21.8 MB
  float* ws    = (float*)d_ws;
  float* x     = ws;                          // [NN][HD]
  float* sA    = x  + (size_t)NN*HD;          // [NN][HD] sbuf ping
  float* sB    = sA + (size_t)NN*HD;          // [NN][HD] sbuf pong
  float* dbuf  = sB + (size_t)NN*HD;          // [NN][HD]
  float* eattr = dbuf + (size_t)NN*HD;        // [E_TOT]
  float* snaps = eattr + E_TOT;               // [7][NV][HD]
  int*   srcA  = (int*)(snaps + (size_t)7*NV*HD);
  int*   srcAV = srcA  + E_AA;
  int*   srcVV = srcAV + E_AV;
  float4* apk  = (float4*)(srcVV + E_VV);     // [NA_PAD] packed atoms
  float4* vpk  = apk + NA_PAD;                // [NV_PAD] packed voxels

  // 1. pack candidates, then merged kNN (dbuf-staged) + init co-resident
  pack_kernel<<<(NA_PAD + NV_PAD + 255)/256, 256, 0, stream>>>(
      atom_pos, vox_pos, apk, vpk);
  knn_all_kernel<<<KNN_BLOCKS + INIT_BLOCKS, 512, 2*KNN_TILE*sizeof(float4), stream>>>(
      atom_pos, vox_pos, apk, vpk, srcA, srcAV, srcVV,
      atom_x, vox_x, W_atom_in, b_atom_in, W_vox_in, b_vox_in,
      ln_g, ln_b, Ws, Wd, x, snaps, sA, dbuf);
  // 2. edge attributes
  edge_attr_kernel<<<(E_TOT + 255)/256, 256, 0, stream>>>(
      atom_pos, vox_pos, srcA, srcAV, srcVV,
      emlp_w1, emlp_b1, emlp_w2, emlp_b2, eattr);
  // 3. 12 fused GAT layers (per-layer dispatch keeps L2 warm across layers)
  for (int l = 0; l < NLAYER; ++l) {
    float* s_in  = (l & 1) ? sB : sA;
    float* s_out = (l & 1) ? sA : sB;
    float* snap  = (l & 1) ? (snaps + (size_t)(l/2 + 1)*NV*HD) : nullptr;
    layer_kernel<<<NGRP, 256, 0, stream>>>(x, s_in, dbuf, s_out, eattr,
                                           srcA, srcAV, srcVV, We, att,
                                           ln_g, ln_b, Ws, Wd, l, snap,
                                           (l < NLAYER-1) ? 1 : 0);
  }
  // 4. output head + vox_pos passthrough
  head_kernel<<<NV/4, 256, 0, stream>>>(snaps, Wo1, bo1, Wo2, bo2, out);
  copy_pos_kernel<<<(NV*3 + 255)/256, 256, 0, stream>>>(vox_pos, out);
}